// Round 1
// baseline (2008.493 us; speedup 1.0000x reference)
//
#include <hip/hip_runtime.h>
#include <cstdint>

// Problem constants
#define TT 512   // KVLEN
#define CC 512   // C
#define HH 8     // heads
#define NN 64    // head dim
#define BQ 32    // BATCH*QLEN
#define NB 4     // BATCH

__device__ __forceinline__ float sigm(float x){ return 1.f/(1.f+__expf(-x)); }

__device__ __forceinline__ float wsum(float x){
  #pragma unroll
  for (int o=32;o;o>>=1) x += __shfl_xor(x, o, 64);
  return x;
}

// ---------------------------------------------------------------------------
// K0: per-bq precompute (32 rows only, since only t=T-1 output survives):
//   Q_w[bq,32], Q_a[bq,32], r_row[bq,512] = xr_last@Wr, g_row[bq,512]
// ---------------------------------------------------------------------------
__global__ __launch_bounds__(256) void k_perbq(
  const float* __restrict__ q, const float* __restrict__ kv,
  const float* __restrict__ x_r, const float* __restrict__ x_w,
  const float* __restrict__ x_a, const float* __restrict__ x_g,
  const float* __restrict__ w1, const float* __restrict__ a1,
  const float* __restrict__ g1, const float* __restrict__ g2,
  const float* __restrict__ Wr,
  float* __restrict__ Qw, float* __restrict__ Qa,
  float* __restrict__ rrow, float* __restrict__ grow)
{
  int bq = blockIdx.x, b = bq >> 3, tid = threadIdx.x;
  __shared__ float xr[CC], xg[CC], qx[CC], gh[96];
  for (int c = tid; c < CC; c += 256){
    float qv = q[bq*CC + c];
    float kl = kv[((size_t)b*TT + (TT-1))*CC + c];
    qx[c] = qv;
    xr[c] = kl + (qv - kl)*x_r[c];
    xg[c] = kl + (qv - kl)*x_g[c];
  }
  __syncthreads();
  if (tid < 32){
    float s = 0.f;
    for (int c = 0; c < CC; c++) s += qx[c]*x_w[c]*w1[c*32 + tid];
    Qw[bq*32 + tid] = s;
  } else if (tid < 64){
    int d = tid - 32; float s = 0.f;
    for (int c = 0; c < CC; c++) s += qx[c]*x_a[c]*a1[c*32 + d];
    Qa[bq*32 + d] = s;
  } else if (tid < 160){
    int d = tid - 64; float s = 0.f;
    for (int c = 0; c < CC; c++) s += xg[c]*g1[c*96 + d];
    gh[d] = sigm(s);
  }
  __syncthreads();
  for (int co = tid; co < CC; co += 256){
    float s = 0.f;
    for (int c = 0; c < CC; c++) s += xr[c]*Wr[c*CC + co];
    rrow[bq*CC + co] = s;
    float sg = 0.f;
    for (int d = 0; d < 96; d++) sg += gh[d]*g2[d*CC + co];
    grow[bq*CC + co] = sg;
  }
}

// ---------------------------------------------------------------------------
// K1: per-(b,t) (2048 rows — xk/xv/sv/P_w/P_a depend only on b, not bq!)
// ---------------------------------------------------------------------------
__global__ __launch_bounds__(256) void k_perbt(
  const float* __restrict__ kv,
  const float* __restrict__ x_k, const float* __restrict__ x_v,
  const float* __restrict__ x_w, const float* __restrict__ x_a,
  const float* __restrict__ w1, const float* __restrict__ a1,
  const float* __restrict__ v0, const float* __restrict__ v1,
  const float* __restrict__ v2,
  float* __restrict__ xk, float* __restrict__ xv,
  float* __restrict__ Pw, float* __restrict__ Pa,
  float* __restrict__ svv)
{
  int bt = blockIdx.x; int t = bt & (TT-1); int tid = threadIdx.x;
  const float* cur = kv + (size_t)bt*CC;
  __shared__ float sxv[CC], sxw[CC], sxa[CC], hv[32];
  for (int c = tid; c < CC; c += 256){
    float x  = cur[c];
    float sh = t ? cur[c - CC] : 0.f;   // token shift within same b
    float d  = sh - x;
    float xkc = x + d*x_k[c];
    float xvc = x + d*x_v[c];
    xk[(size_t)bt*CC + c] = xkc;
    xv[(size_t)bt*CC + c] = xvc;
    sxv[c] = xvc;
    sxw[c] = x*(1.f - x_w[c]);
    sxa[c] = x*(1.f - x_a[c]);
  }
  __syncthreads();
  if (tid < 32){
    float s = 0.f; for (int c = 0; c < CC; c++) s += sxw[c]*w1[c*32 + tid];
    Pw[bt*32 + tid] = s;
  } else if (tid < 64){
    int d = tid - 32; float s = 0.f;
    for (int c = 0; c < CC; c++) s += sxa[c]*a1[c*32 + d];
    Pa[bt*32 + d] = s;
  } else if (tid < 96){
    int d = tid - 64; float s = 0.f;
    for (int c = 0; c < CC; c++) s += sxv[c]*v1[c*32 + d];
    hv[d] = s;
  }
  __syncthreads();
  for (int c = tid; c < CC; c += 256){
    float s = 0.f;
    #pragma unroll
    for (int d = 0; d < 32; d++) s += hv[d]*v2[d*CC + c];
    svv[(size_t)bt*CC + c] = sigm(v0[c] + s);
  }
}

// ---------------------------------------------------------------------------
// Tiled fp32 GEMM: C[2048x512] = A[2048x512] @ W[512x512]. 64x64 tile, 4x4/thread.
// ---------------------------------------------------------------------------
__global__ __launch_bounds__(256) void gemm_2048_512(
  const float* __restrict__ A, const float* __restrict__ W, float* __restrict__ Co)
{
  __shared__ float As[32][68];   // [k][m], padded
  __shared__ float Bs[32][64];   // [k][n]
  int tid = threadIdx.x;
  int tx = tid & 15, ty = tid >> 4;
  int m0 = blockIdx.y*64, n0 = blockIdx.x*64;
  float acc[4][4];
  #pragma unroll
  for (int i=0;i<4;i++)
    #pragma unroll
    for (int j=0;j<4;j++) acc[i][j]=0.f;

  for (int k0 = 0; k0 < 512; k0 += 32){
    #pragma unroll
    for (int i = 0; i < 8; i++){
      int e = tid + i*256;
      int kk = e & 31, m = e >> 5;
      As[kk][m] = A[(size_t)(m0+m)*512 + k0 + kk];
    }
    #pragma unroll
    for (int i = 0; i < 8; i++){
      int e = tid + i*256;
      int n = e & 63, kk = e >> 6;
      Bs[kk][n] = W[(size_t)(k0+kk)*512 + n0 + n];
    }
    __syncthreads();
    #pragma unroll
    for (int kk = 0; kk < 32; kk++){
      float a4[4], b4[4];
      #pragma unroll
      for (int i=0;i<4;i++) a4[i] = As[kk][ty*4+i];
      #pragma unroll
      for (int j=0;j<4;j++) b4[j] = Bs[kk][tx*4+j];
      #pragma unroll
      for (int i=0;i<4;i++)
        #pragma unroll
        for (int j=0;j<4;j++) acc[i][j] += a4[i]*b4[j];
    }
    __syncthreads();
  }
  #pragma unroll
  for (int i=0;i<4;i++)
    #pragma unroll
    for (int j=0;j<4;j++)
      Co[(size_t)(m0+ty*4+i)*512 + n0 + tx*4 + j] = acc[i][j];
}

// ---------------------------------------------------------------------------
// K1b: kk = normalize_per_head(k * k_k)  (per-b, 2048 rows)
// ---------------------------------------------------------------------------
__global__ __launch_bounds__(512) void k_kk(
  const float* __restrict__ kg, const float* __restrict__ k_k,
  float* __restrict__ kkg)
{
  int bt = blockIdx.x, tid = threadIdx.x;     // tid = c; head = tid>>6 (wave-aligned)
  float v = kg[(size_t)bt*CC + tid]*k_k[tid];
  float ss = wsum(v*v);
  float nrm = fmaxf(sqrtf(ss), 1e-12f);
  kkg[(size_t)bt*CC + tid] = v/nrm;
}

// ---------------------------------------------------------------------------
// K2a: th = tanh(Pw+Qw), al = Pa+Qa   (16384 x 32 each)
// ---------------------------------------------------------------------------
__global__ __launch_bounds__(256) void k_thal(
  const float* __restrict__ Pw, const float* __restrict__ Pa,
  const float* __restrict__ Qw, const float* __restrict__ Qa,
  float* __restrict__ th, float* __restrict__ al)
{
  int idx = blockIdx.x*256 + threadIdx.x;       // [0, 524288)
  int bqt = idx >> 5, d = idx & 31;
  int bq = bqt >> 9, t = bqt & (TT-1), b = bq >> 3;
  int pidx = ((b << 9) | t)*32 + d;
  th[idx] = tanhf(Pw[pidx] + Qw[bq*32 + d]);
  al[idx] = Pa[pidx] + Qa[bq*32 + d];
}

// ---------------------------------------------------------------------------
// K2: per (bq,t,c): decay w, k_final, b_vec = kk*a  (the 3 bq-dependent scan inputs)
//   w = exp(-e^{-0.5} * sigmoid(w0 + th@w2))   [identity: -softplus(-x)-0.5 form]
//   a = sigmoid(a0 + al@a2); kf = k*(1+(a-1)*k_a); bv = kk*a
// ---------------------------------------------------------------------------
__global__ __launch_bounds__(256) void k_wkb(
  const float* __restrict__ th, const float* __restrict__ al,
  const float* __restrict__ w2, const float* __restrict__ a2,
  const float* __restrict__ w0, const float* __restrict__ a0,
  const float* __restrict__ k_a, const float* __restrict__ kg,
  const float* __restrict__ kkg,
  float* __restrict__ wS, float* __restrict__ kS, float* __restrict__ bS)
{
  int bqt = blockIdx.x; int bq = bqt >> 9, t = bqt & (TT-1), b = bq >> 3;
  size_t bt = (size_t)((b << 9) | t);
  const float* thp = th + (size_t)bqt*32;
  const float* alp = al + (size_t)bqt*32;
  float thr[32], alr[32];
  #pragma unroll
  for (int d = 0; d < 32; d++){ thr[d] = thp[d]; alr[d] = alp[d]; }
  #pragma unroll
  for (int cc = 0; cc < 2; cc++){
    int c = threadIdx.x + cc*256;
    float w0a=0,w1a=0,a0a=0,a1a=0;
    #pragma unroll
    for (int d = 0; d < 32; d += 2){
      w0a += thr[d]  *w2[d*CC + c];
      w1a += thr[d+1]*w2[(d+1)*CC + c];
      a0a += alr[d]  *a2[d*CC + c];
      a1a += alr[d+1]*a2[(d+1)*CC + c];
    }
    float a_sig = sigm(a0[c] + a0a + a1a);
    float wdec  = __expf(-0.60653066f * sigm(w0[c] + w0a + w1a));
    float kvv = kg[bt*CC + c];
    float kkv = kkg[bt*CC + c];
    size_t o = (size_t)bqt*CC + c;
    wS[o] = wdec;
    kS[o] = kvv*(1.f + (a_sig - 1.f)*k_a[c]);
    bS[o] = kkv*a_sig;
  }
}

// ---------------------------------------------------------------------------
// K3: the sequential scan. One wave per (bq,h); lane = row i of the 64x64 state.
// Per step: sa_i = -sum_j S[i,j]*kk[j];  S[i,j] = S[i,j]*w[j] + sa_i*b[j] + v_i*k[j]
// Vectors w/k/b/kk are wave-uniform (s_load); v_i is 3 per-lane loads (v lerp fused).
// Epilogue (t=511 only): out = S@r, groupnorm over lanes, +rk*v, *g.
// ---------------------------------------------------------------------------
__global__ __launch_bounds__(64) void k_scan(
  const float* __restrict__ wv, const float* __restrict__ kf,
  const float* __restrict__ bv, const float* __restrict__ kkg,
  const float* __restrict__ vpre, const float* __restrict__ svv,
  const float* __restrict__ vfirst,
  const float* __restrict__ rrow, const float* __restrict__ grow,
  const float* __restrict__ r_k, const float* __restrict__ ln_w,
  const float* __restrict__ ln_b, float* __restrict__ xo)
{
  int blk = blockIdx.x; int bq = blk >> 3, h = blk & 7, b = bq >> 3;
  int lane = threadIdx.x;
  float st[NN];
  #pragma unroll
  for (int j = 0; j < NN; j++) st[j] = 0.f;
  size_t base_bq = ((size_t)bq*TT)*CC + h*NN;
  size_t base_b  = ((size_t)b*TT)*CC + h*NN;
  float v_i = 0.f;
  for (int t = 0; t < TT; t++){
    size_t obq = base_bq + (size_t)t*CC;
    size_t ob  = base_b  + (size_t)t*CC;
    const float* wp = wv  + obq;
    const float* kp = kf  + obq;
    const float* bp = bv  + obq;
    const float* ap = kkg + ob;     // a_t = -kk (negation folded into sa)
    float vp = vpre[ob + lane];
    float sv = svv[ob + lane];
    float vf = vfirst[obq + lane];
    v_i = vp + (vf - vp)*sv;
    float s0=0,s1=0,s2=0,s3=0;
    #pragma unroll
    for (int j = 0; j < NN; j += 4){
      s0 += st[j  ]*ap[j  ];
      s1 += st[j+1]*ap[j+1];
      s2 += st[j+2]*ap[j+2];
      s3 += st[j+3]*ap[j+3];
    }
    float sa = -((s0+s1)+(s2+s3));
    #pragma unroll
    for (int j = 0; j < NN; j++){
      st[j] = st[j]*wp[j] + (sa*bp[j] + v_i*kp[j]);
    }
  }
  // epilogue at t = T-1
  const float* rp = rrow + bq*CC + h*NN;
  float o0=0,o1=0,o2=0,o3=0;
  #pragma unroll
  for (int j = 0; j < NN; j += 4){
    o0 += st[j  ]*rp[j  ];
    o1 += st[j+1]*rp[j+1];
    o2 += st[j+2]*rp[j+2];
    o3 += st[j+3]*rp[j+3];
  }
  float out = (o0+o1)+(o2+o3);
  float mean = wsum(out) * (1.f/NN);
  float dv = out - mean;
  float var = wsum(dv*dv) * (1.f/NN);
  float yn = dv * rsqrtf(var + 6.4e-4f);   // GN_EPS = 1e-5*64
  int c = h*NN + lane;
  float y2 = yn * ln_w[c] + ln_b[c];
  float kl = kf[base_bq + (size_t)(TT-1)*CC + lane];
  float rl = rp[lane];
  float rk = wsum(rl*kl*r_k[c]);
  float res = (y2 + rk*v_i) * grow[bq*CC + c];
  xo[bq*CC + c] = res;
}

// ---------------------------------------------------------------------------
// K4: out[bq,:] = xo_pre[bq,:] @ Wo   (32 x 512 x 512)
// ---------------------------------------------------------------------------
__global__ __launch_bounds__(256) void k_out(
  const float* __restrict__ xo, const float* __restrict__ Wo,
  float* __restrict__ outp)
{
  int bq = blockIdx.x, tid = threadIdx.x;
  __shared__ float row[CC];
  for (int c = tid; c < CC; c += 256) row[c] = xo[bq*CC + c];
  __syncthreads();
  for (int co = tid; co < CC; co += 256){
    float s0=0, s1=0;
    for (int c = 0; c < CC; c += 2){
      s0 += row[c  ]*Wo[(size_t)c*CC + co];
      s1 += row[c+1]*Wo[(size_t)(c+1)*CC + co];
    }
    outp[bq*CC + co] = s0 + s1;
  }
}

// ---------------------------------------------------------------------------
extern "C" void kernel_launch(void* const* d_in, const int* in_sizes, int n_in,
                              void* d_out, int out_size, void* d_ws, size_t ws_size,
                              hipStream_t stream)
{
  const float* q   = (const float*)d_in[0];
  const float* kv  = (const float*)d_in[1];
  const float* vf  = (const float*)d_in[2];
  const float* x_r = (const float*)d_in[3];
  const float* x_w = (const float*)d_in[4];
  const float* x_k = (const float*)d_in[5];
  const float* x_v = (const float*)d_in[6];
  const float* x_a = (const float*)d_in[7];
  const float* x_g = (const float*)d_in[8];
  const float* w0  = (const float*)d_in[9];
  const float* w1  = (const float*)d_in[10];
  const float* w2  = (const float*)d_in[11];
  const float* a0  = (const float*)d_in[12];
  const float* a1  = (const float*)d_in[13];
  const float* a2  = (const float*)d_in[14];
  const float* v0  = (const float*)d_in[15];
  const float* v1  = (const float*)d_in[16];
  const float* v2  = (const float*)d_in[17];
  const float* g1  = (const float*)d_in[18];
  const float* g2  = (const float*)d_in[19];
  const float* k_k = (const float*)d_in[20];
  const float* k_a = (const float*)d_in[21];
  const float* r_k = (const float*)d_in[22];
  const float* Wr  = (const float*)d_in[23];
  const float* Wk  = (const float*)d_in[24];
  const float* Wv  = (const float*)d_in[25];
  const float* Wo  = (const float*)d_in[26];
  const float* lnw = (const float*)d_in[27];
  const float* lnb = (const float*)d_in[28];
  float* outp = (float*)d_out;
  float* ws = (float*)d_ws;

  // workspace layout (floats) — total ~32.7M floats ≈ 131 MB
  float* xk = ws + 0;         // 4*512*512
  float* xv = ws + 1048576;   // 4*512*512
  float* kg = ws + 2097152;   // k
  float* vp = ws + 3145728;   // v_pre
  float* sv = ws + 4194304;   // sigmoid lerp factor
  float* kk = ws + 5242880;   // normalized kk
  float* Pw = ws + 6291456;   // 4*512*32
  float* Pa = ws + 6356992;
  float* Qw = ws + 6422528;   // 32*32
  float* Qa = ws + 6423552;
  float* th = ws + 6424576;   // 32*512*32
  float* al = ws + 6948864;
  float* rr = ws + 7473152;   // 32*512
  float* gr = ws + 7489536;
  float* xo = ws + 7505920;
  float* wS = ws + 7522304;   // 32*512*512 decay
  float* kS = ws + 15910912;  // k_final
  float* bS = ws + 24299520;  // kk*a

  // v_first passthrough (tuple output #2)
  hipMemcpyAsync(outp + BQ*CC /*16384*/, vf,
                 (size_t)BQ*TT*CC*sizeof(float), hipMemcpyDeviceToDevice, stream);

  k_perbq<<<32, 256, 0, stream>>>(q, kv, x_r, x_w, x_a, x_g, w1, a1, g1, g2, Wr,
                                  Qw, Qa, rr, gr);
  k_perbt<<<NB*TT, 256, 0, stream>>>(kv, x_k, x_v, x_w, x_a, w1, a1, v0, v1, v2,
                                     xk, xv, Pw, Pa, sv);
  gemm_2048_512<<<dim3(8, 32), 256, 0, stream>>>(xk, Wk, kg);
  gemm_2048_512<<<dim3(8, 32), 256, 0, stream>>>(xv, Wv, vp);
  k_kk<<<NB*TT, 512, 0, stream>>>(kg, k_k, kk);
  k_thal<<<2048, 256, 0, stream>>>(Pw, Pa, Qw, Qa, th, al);
  k_wkb<<<BQ*TT, 256, 0, stream>>>(th, al, w2, a2, w0, a0, k_a, kg, kk, wS, kS, bS);
  k_scan<<<BQ*HH, 64, 0, stream>>>(wS, kS, bS, kk, vp, sv, vf, rr, gr, r_k,
                                   lnw, lnb, xo);
  k_out<<<32, 256, 0, stream>>>(xo, Wo, outp);
}

// Round 2
// 1163.784 us; speedup vs baseline: 1.7258x; 1.7258x over previous
//
#include <hip/hip_runtime.h>
#include <cstdint>

// Problem constants
#define TT 512   // KVLEN
#define CC 512   // C
#define HH 8     // heads
#define NN 64    // head dim
#define BQ 32    // BATCH*QLEN
#define NB 4     // BATCH

__device__ __forceinline__ float sigm(float x){ return 1.f/(1.f+__expf(-x)); }

__device__ __forceinline__ float wsum(float x){
  #pragma unroll
  for (int o=32;o;o>>=1) x += __shfl_xor(x, o, 64);
  return x;
}

// ---------------------------------------------------------------------------
// K0: per-bq precompute (32 rows only, since only t=T-1 output survives):
//   Q_w[bq,32], Q_a[bq,32], r_row[bq,512] = xr_last@Wr, g_row[bq,512]
// ---------------------------------------------------------------------------
__global__ __launch_bounds__(256) void k_perbq(
  const float* __restrict__ q, const float* __restrict__ kv,
  const float* __restrict__ x_r, const float* __restrict__ x_w,
  const float* __restrict__ x_a, const float* __restrict__ x_g,
  const float* __restrict__ w1, const float* __restrict__ a1,
  const float* __restrict__ g1, const float* __restrict__ g2,
  const float* __restrict__ Wr,
  float* __restrict__ Qw, float* __restrict__ Qa,
  float* __restrict__ rrow, float* __restrict__ grow)
{
  int bq = blockIdx.x, b = bq >> 3, tid = threadIdx.x;
  __shared__ float xr[CC], xg[CC], qx[CC], gh[96];
  for (int c = tid; c < CC; c += 256){
    float qv = q[bq*CC + c];
    float kl = kv[((size_t)b*TT + (TT-1))*CC + c];
    qx[c] = qv;
    xr[c] = kl + (qv - kl)*x_r[c];
    xg[c] = kl + (qv - kl)*x_g[c];
  }
  __syncthreads();
  if (tid < 32){
    float s = 0.f;
    for (int c = 0; c < CC; c++) s += qx[c]*x_w[c]*w1[c*32 + tid];
    Qw[bq*32 + tid] = s;
  } else if (tid < 64){
    int d = tid - 32; float s = 0.f;
    for (int c = 0; c < CC; c++) s += qx[c]*x_a[c]*a1[c*32 + d];
    Qa[bq*32 + d] = s;
  } else if (tid < 160){
    int d = tid - 64; float s = 0.f;
    for (int c = 0; c < CC; c++) s += xg[c]*g1[c*96 + d];
    gh[d] = sigm(s);
  }
  __syncthreads();
  for (int co = tid; co < CC; co += 256){
    float s = 0.f;
    for (int c = 0; c < CC; c++) s += xr[c]*Wr[c*CC + co];
    rrow[bq*CC + co] = s;
    float sg = 0.f;
    for (int d = 0; d < 96; d++) sg += gh[d]*g2[d*CC + co];
    grow[bq*CC + co] = sg;
  }
}

// ---------------------------------------------------------------------------
// K1: per-(b,t) (2048 rows — xk/xv/sv/P_w/P_a depend only on b, not bq!)
// ---------------------------------------------------------------------------
__global__ __launch_bounds__(256) void k_perbt(
  const float* __restrict__ kv,
  const float* __restrict__ x_k, const float* __restrict__ x_v,
  const float* __restrict__ x_w, const float* __restrict__ x_a,
  const float* __restrict__ w1, const float* __restrict__ a1,
  const float* __restrict__ v0, const float* __restrict__ v1,
  const float* __restrict__ v2,
  float* __restrict__ xk, float* __restrict__ xv,
  float* __restrict__ Pw, float* __restrict__ Pa,
  float* __restrict__ svv)
{
  int bt = blockIdx.x; int t = bt & (TT-1); int tid = threadIdx.x;
  const float* cur = kv + (size_t)bt*CC;
  __shared__ float sxv[CC], sxw[CC], sxa[CC], hv[32];
  for (int c = tid; c < CC; c += 256){
    float x  = cur[c];
    float sh = t ? cur[c - CC] : 0.f;   // token shift within same b
    float d  = sh - x;
    float xkc = x + d*x_k[c];
    float xvc = x + d*x_v[c];
    xk[(size_t)bt*CC + c] = xkc;
    xv[(size_t)bt*CC + c] = xvc;
    sxv[c] = xvc;
    sxw[c] = x*(1.f - x_w[c]);
    sxa[c] = x*(1.f - x_a[c]);
  }
  __syncthreads();
  if (tid < 32){
    float s = 0.f; for (int c = 0; c < CC; c++) s += sxw[c]*w1[c*32 + tid];
    Pw[bt*32 + tid] = s;
  } else if (tid < 64){
    int d = tid - 32; float s = 0.f;
    for (int c = 0; c < CC; c++) s += sxa[c]*a1[c*32 + d];
    Pa[bt*32 + d] = s;
  } else if (tid < 96){
    int d = tid - 64; float s = 0.f;
    for (int c = 0; c < CC; c++) s += sxv[c]*v1[c*32 + d];
    hv[d] = s;
  }
  __syncthreads();
  for (int c = tid; c < CC; c += 256){
    float s = 0.f;
    #pragma unroll
    for (int d = 0; d < 32; d++) s += hv[d]*v2[d*CC + c];
    svv[(size_t)bt*CC + c] = sigm(v0[c] + s);
  }
}

// ---------------------------------------------------------------------------
// Tiled fp32 GEMM: C[2048x512] = A[2048x512] @ W[512x512]. 64x64 tile, 4x4/thread.
// ---------------------------------------------------------------------------
__global__ __launch_bounds__(256) void gemm_2048_512(
  const float* __restrict__ A, const float* __restrict__ W, float* __restrict__ Co)
{
  __shared__ float As[32][68];   // [k][m], padded
  __shared__ float Bs[32][64];   // [k][n]
  int tid = threadIdx.x;
  int tx = tid & 15, ty = tid >> 4;
  int m0 = blockIdx.y*64, n0 = blockIdx.x*64;
  float acc[4][4];
  #pragma unroll
  for (int i=0;i<4;i++)
    #pragma unroll
    for (int j=0;j<4;j++) acc[i][j]=0.f;

  for (int k0 = 0; k0 < 512; k0 += 32){
    #pragma unroll
    for (int i = 0; i < 8; i++){
      int e = tid + i*256;
      int kk = e & 31, m = e >> 5;
      As[kk][m] = A[(size_t)(m0+m)*512 + k0 + kk];
    }
    #pragma unroll
    for (int i = 0; i < 8; i++){
      int e = tid + i*256;
      int n = e & 63, kk = e >> 6;
      Bs[kk][n] = W[(size_t)(k0+kk)*512 + n0 + n];
    }
    __syncthreads();
    #pragma unroll
    for (int kk = 0; kk < 32; kk++){
      float a4[4], b4[4];
      #pragma unroll
      for (int i=0;i<4;i++) a4[i] = As[kk][ty*4+i];
      #pragma unroll
      for (int j=0;j<4;j++) b4[j] = Bs[kk][tx*4+j];
      #pragma unroll
      for (int i=0;i<4;i++)
        #pragma unroll
        for (int j=0;j<4;j++) acc[i][j] += a4[i]*b4[j];
    }
    __syncthreads();
  }
  #pragma unroll
  for (int i=0;i<4;i++)
    #pragma unroll
    for (int j=0;j<4;j++)
      Co[(size_t)(m0+ty*4+i)*512 + n0 + tx*4 + j] = acc[i][j];
}

// ---------------------------------------------------------------------------
// K1b: kk = normalize_per_head(k * k_k)  (per-b, 2048 rows)
// ---------------------------------------------------------------------------
__global__ __launch_bounds__(512) void k_kk(
  const float* __restrict__ kg, const float* __restrict__ k_k,
  float* __restrict__ kkg)
{
  int bt = blockIdx.x, tid = threadIdx.x;     // tid = c; head = tid>>6 (wave-aligned)
  float v = kg[(size_t)bt*CC + tid]*k_k[tid];
  float ss = wsum(v*v);
  float nrm = fmaxf(sqrtf(ss), 1e-12f);
  kkg[(size_t)bt*CC + tid] = v/nrm;
}

// ---------------------------------------------------------------------------
// K2a: th = tanh(Pw+Qw), al = Pa+Qa   (16384 x 32 each)
// ---------------------------------------------------------------------------
__global__ __launch_bounds__(256) void k_thal(
  const float* __restrict__ Pw, const float* __restrict__ Pa,
  const float* __restrict__ Qw, const float* __restrict__ Qa,
  float* __restrict__ th, float* __restrict__ al)
{
  int idx = blockIdx.x*256 + threadIdx.x;       // [0, 524288)
  int bqt = idx >> 5, d = idx & 31;
  int bq = bqt >> 9, t = bqt & (TT-1), b = bq >> 3;
  int pidx = ((b << 9) | t)*32 + d;
  th[idx] = tanhf(Pw[pidx] + Qw[bq*32 + d]);
  al[idx] = Pa[pidx] + Qa[bq*32 + d];
}

// ---------------------------------------------------------------------------
// K2: per (bq,t,c): decay w, k_final, b_vec = kk*a  (the 3 bq-dependent scan inputs)
// ---------------------------------------------------------------------------
__global__ __launch_bounds__(256) void k_wkb(
  const float* __restrict__ th, const float* __restrict__ al,
  const float* __restrict__ w2, const float* __restrict__ a2,
  const float* __restrict__ w0, const float* __restrict__ a0,
  const float* __restrict__ k_a, const float* __restrict__ kg,
  const float* __restrict__ kkg,
  float* __restrict__ wS, float* __restrict__ kS, float* __restrict__ bS)
{
  int bqt = blockIdx.x; int bq = bqt >> 9, t = bqt & (TT-1), b = bq >> 3;
  size_t bt = (size_t)((b << 9) | t);
  const float* thp = th + (size_t)bqt*32;
  const float* alp = al + (size_t)bqt*32;
  float thr[32], alr[32];
  #pragma unroll
  for (int d = 0; d < 32; d++){ thr[d] = thp[d]; alr[d] = alp[d]; }
  #pragma unroll
  for (int cc = 0; cc < 2; cc++){
    int c = threadIdx.x + cc*256;
    float w0a=0,w1a=0,a0a=0,a1a=0;
    #pragma unroll
    for (int d = 0; d < 32; d += 2){
      w0a += thr[d]  *w2[d*CC + c];
      w1a += thr[d+1]*w2[(d+1)*CC + c];
      a0a += alr[d]  *a2[d*CC + c];
      a1a += alr[d+1]*a2[(d+1)*CC + c];
    }
    float a_sig = sigm(a0[c] + a0a + a1a);
    float wdec  = __expf(-0.60653066f * sigm(w0[c] + w0a + w1a));
    float kvv = kg[bt*CC + c];
    float kkv = kkg[bt*CC + c];
    size_t o = (size_t)bqt*CC + c;
    wS[o] = wdec;
    kS[o] = kvv*(1.f + (a_sig - 1.f)*k_a[c]);
    bS[o] = kkv*a_sig;
  }
}

// ---------------------------------------------------------------------------
// K3: sequential scan, software-pipelined.
// One wave per (bq,h); lane = row i of the 64x64 state, st[j] in VGPRs.
// Staging: lane l loads {w_t[l], k_t[l], b_t[l], kk_{t+1}[l]} coalesced, packs
// into LDS float4 double buffer one step ahead. Compute reads LDS with
// uniform-address ds_read_b128 (broadcast, conflict-free).
// sa for step t+1 is accumulated DURING step t's update pass (st_new · kk_{t+1}),
// so each step starts with sa ready (no separate dot pass).
// ---------------------------------------------------------------------------
__global__ __launch_bounds__(64, 1) void k_scan(
  const float* __restrict__ wv, const float* __restrict__ kf,
  const float* __restrict__ bv, const float* __restrict__ kkg,
  const float* __restrict__ vpre, const float* __restrict__ svv,
  const float* __restrict__ vfirst,
  const float* __restrict__ rrow, const float* __restrict__ grow,
  const float* __restrict__ r_k, const float* __restrict__ ln_w,
  const float* __restrict__ ln_b, float* __restrict__ xo)
{
  __shared__ float4 lds[2][NN];
  int blk = blockIdx.x; int bq = blk >> 3, h = blk & 7, b = bq >> 3;
  int lane = threadIdx.x;
  float st[NN];
  #pragma unroll
  for (int j = 0; j < NN; j++) st[j] = 0.f;

  size_t base_bq = ((size_t)bq*TT)*CC + h*NN + lane;   // per-lane element addr
  size_t base_b  = ((size_t)b*TT)*CC + h*NN + lane;

  // stage step 0: {w_0, k_0, b_0, kk_1}
  {
    float w0r = wv[base_bq];
    float k0r = kf[base_bq];
    float b0r = bv[base_bq];
    float a0r = kkg[base_b + CC];       // kk at t=1 (TT>1)
    lds[0][lane] = make_float4(w0r, k0r, b0r, a0r);
  }
  float vp_r = vpre[base_b], sv_r = svv[base_b], vf_r = vfirst[base_bq];

  float sac = 0.f;      // sa consumed this step (st=0 at t=0 -> 0)
  float v_last = 0.f;

  for (int t = 0; t < TT; t++){
    int cur = t & 1;
    // prefetch step t+1 (no wait yet)
    float w_n=0.f, k_n=0.f, b_n=0.f, a_n=0.f, vp_n=0.f, sv_n=0.f, vf_n=0.f;
    if (t < TT-1){
      size_t obq = base_bq + (size_t)(t+1)*CC;
      size_t ob  = base_b  + (size_t)(t+1)*CC;
      w_n = wv[obq]; k_n = kf[obq]; b_n = bv[obq];
      int t2 = (t+2 < TT) ? (t+2) : (TT-1);
      a_n = kkg[base_b + (size_t)t2*CC];
      vp_n = vpre[ob]; sv_n = svv[ob]; vf_n = vfirst[obq];
    }
    float v_i = vp_r + (vf_r - vp_r)*sv_r;
    v_last = v_i;

    float sn0=0.f, sn1=0.f, sn2=0.f, sn3=0.f;
    #pragma unroll
    for (int j = 0; j < NN; j += 4){
      float4 q0 = lds[cur][j  ];
      float4 q1 = lds[cur][j+1];
      float4 q2 = lds[cur][j+2];
      float4 q3 = lds[cur][j+3];
      st[j  ] = fmaf(st[j  ], q0.x, fmaf(sac, q0.z, v_i*q0.y));
      st[j+1] = fmaf(st[j+1], q1.x, fmaf(sac, q1.z, v_i*q1.y));
      st[j+2] = fmaf(st[j+2], q2.x, fmaf(sac, q2.z, v_i*q2.y));
      st[j+3] = fmaf(st[j+3], q3.x, fmaf(sac, q3.z, v_i*q3.y));
      sn0 = fmaf(st[j  ], q0.w, sn0);
      sn1 = fmaf(st[j+1], q1.w, sn1);
      sn2 = fmaf(st[j+2], q2.w, sn2);
      sn3 = fmaf(st[j+3], q3.w, sn3);
    }
    sac = -((sn0+sn1)+(sn2+sn3));   // sa for step t+1 (a = -kk)

    if (t < TT-1){
      lds[cur^1][lane] = make_float4(w_n, k_n, b_n, a_n);
      vp_r = vp_n; sv_r = sv_n; vf_r = vf_n;
    }
  }

  // epilogue at t = T-1
  const float* rp = rrow + bq*CC + h*NN;
  float o0=0,o1=0,o2=0,o3=0;
  #pragma unroll
  for (int j = 0; j < NN; j += 4){
    o0 += st[j  ]*rp[j  ];
    o1 += st[j+1]*rp[j+1];
    o2 += st[j+2]*rp[j+2];
    o3 += st[j+3]*rp[j+3];
  }
  float out = (o0+o1)+(o2+o3);
  float mean = wsum(out) * (1.f/NN);
  float dv = out - mean;
  float var = wsum(dv*dv) * (1.f/NN);
  float yn = dv * rsqrtf(var + 6.4e-4f);   // GN_EPS = 1e-5*64
  int c = h*NN + lane;
  float y2 = yn * ln_w[c] + ln_b[c];
  float kl = kf[base_bq + (size_t)(TT-1)*CC];
  float rl = rp[lane];
  float rk = wsum(rl*kl*r_k[c]);
  float res = (y2 + rk*v_last) * grow[bq*CC + c];
  xo[bq*CC + c] = res;
}

// ---------------------------------------------------------------------------
// K4: out[bq,:] = xo_pre[bq,:] @ Wo   (32 x 512 x 512)
// ---------------------------------------------------------------------------
__global__ __launch_bounds__(256) void k_out(
  const float* __restrict__ xo, const float* __restrict__ Wo,
  float* __restrict__ outp)
{
  int bq = blockIdx.x, tid = threadIdx.x;
  __shared__ float row[CC];
  for (int c = tid; c < CC; c += 256) row[c] = xo[bq*CC + c];
  __syncthreads();
  for (int co = tid; co < CC; co += 256){
    float s0=0, s1=0;
    for (int c = 0; c < CC; c += 2){
      s0 += row[c  ]*Wo[(size_t)c*CC + co];
      s1 += row[c+1]*Wo[(size_t)(c+1)*CC + co];
    }
    outp[bq*CC + co] = s0 + s1;
  }
}

// ---------------------------------------------------------------------------
extern "C" void kernel_launch(void* const* d_in, const int* in_sizes, int n_in,
                              void* d_out, int out_size, void* d_ws, size_t ws_size,
                              hipStream_t stream)
{
  const float* q   = (const float*)d_in[0];
  const float* kv  = (const float*)d_in[1];
  const float* vf  = (const float*)d_in[2];
  const float* x_r = (const float*)d_in[3];
  const float* x_w = (const float*)d_in[4];
  const float* x_k = (const float*)d_in[5];
  const float* x_v = (const float*)d_in[6];
  const float* x_a = (const float*)d_in[7];
  const float* x_g = (const float*)d_in[8];
  const float* w0  = (const float*)d_in[9];
  const float* w1  = (const float*)d_in[10];
  const float* w2  = (const float*)d_in[11];
  const float* a0  = (const float*)d_in[12];
  const float* a1  = (const float*)d_in[13];
  const float* a2  = (const float*)d_in[14];
  const float* v0  = (const float*)d_in[15];
  const float* v1  = (const float*)d_in[16];
  const float* v2  = (const float*)d_in[17];
  const float* g1  = (const float*)d_in[18];
  const float* g2  = (const float*)d_in[19];
  const float* k_k = (const float*)d_in[20];
  const float* k_a = (const float*)d_in[21];
  const float* r_k = (const float*)d_in[22];
  const float* Wr  = (const float*)d_in[23];
  const float* Wk  = (const float*)d_in[24];
  const float* Wv  = (const float*)d_in[25];
  const float* Wo  = (const float*)d_in[26];
  const float* lnw = (const float*)d_in[27];
  const float* lnb = (const float*)d_in[28];
  float* outp = (float*)d_out;
  float* ws = (float*)d_ws;

  // workspace layout (floats) — total ~32.7M floats ≈ 131 MB
  float* xk = ws + 0;         // 4*512*512
  float* xv = ws + 1048576;   // 4*512*512
  float* kg = ws + 2097152;   // k
  float* vp = ws + 3145728;   // v_pre
  float* sv = ws + 4194304;   // sigmoid lerp factor
  float* kk = ws + 5242880;   // normalized kk
  float* Pw = ws + 6291456;   // 4*512*32
  float* Pa = ws + 6356992;
  float* Qw = ws + 6422528;   // 32*32
  float* Qa = ws + 6423552;
  float* th = ws + 6424576;   // 32*512*32
  float* al = ws + 6948864;
  float* rr = ws + 7473152;   // 32*512
  float* gr = ws + 7489536;
  float* xo = ws + 7505920;
  float* wS = ws + 7522304;   // 32*512*512 decay
  float* kS = ws + 15910912;  // k_final
  float* bS = ws + 24299520;  // kk*a

  // v_first passthrough (tuple output #2)
  hipMemcpyAsync(outp + BQ*CC /*16384*/, vf,
                 (size_t)BQ*TT*CC*sizeof(float), hipMemcpyDeviceToDevice, stream);

  k_perbq<<<32, 256, 0, stream>>>(q, kv, x_r, x_w, x_a, x_g, w1, a1, g1, g2, Wr,
                                  Qw, Qa, rr, gr);
  k_perbt<<<NB*TT, 256, 0, stream>>>(kv, x_k, x_v, x_w, x_a, w1, a1, v0, v1, v2,
                                     xk, xv, Pw, Pa, sv);
  gemm_2048_512<<<dim3(8, 32), 256, 0, stream>>>(xk, Wk, kg);
  gemm_2048_512<<<dim3(8, 32), 256, 0, stream>>>(xv, Wv, vp);
  k_kk<<<NB*TT, 512, 0, stream>>>(kg, k_k, kk);
  k_thal<<<2048, 256, 0, stream>>>(Pw, Pa, Qw, Qa, th, al);
  k_wkb<<<BQ*TT, 256, 0, stream>>>(th, al, w2, a2, w0, a0, k_a, kg, kk, wS, kS, bS);
  k_scan<<<BQ*HH, 64, 0, stream>>>(wS, kS, bS, kk, vp, sv, vf, rr, gr, r_k,
                                   lnw, lnb, xo);
  k_out<<<32, 256, 0, stream>>>(xo, Wo, outp);
}

// Round 4
// 1112.360 us; speedup vs baseline: 1.8056x; 1.0462x over previous
//
#include <hip/hip_runtime.h>
#include <cstdint>

// Problem constants
#define TT 512   // KVLEN
#define CC 512   // C
#define HH 8     // heads
#define NN 64    // head dim
#define BQ 32    // BATCH*QLEN
#define NB 4     // BATCH

__device__ __forceinline__ float sigm(float x){ return 1.f/(1.f+__expf(-x)); }

__device__ __forceinline__ float wsum(float x){
  #pragma unroll
  for (int o=32;o;o>>=1) x += __shfl_xor(x, o, 64);
  return x;
}

// ---------------------------------------------------------------------------
// k_prep: per-bq small dots (32 blocks): Qw[bq,32], Qa[bq,32], gh[bq,96],
// and xr row -> workspace. Each dot is one wave: 8 elems/lane + wsum.
// ---------------------------------------------------------------------------
__global__ __launch_bounds__(256) void k_prep(
  const float* __restrict__ q, const float* __restrict__ kv,
  const float* __restrict__ x_r, const float* __restrict__ x_w,
  const float* __restrict__ x_a, const float* __restrict__ x_g,
  const float* __restrict__ w1, const float* __restrict__ a1,
  const float* __restrict__ g1,
  float* __restrict__ Qw, float* __restrict__ Qa,
  float* __restrict__ ghw, float* __restrict__ xrw)
{
  int bq = blockIdx.x, b = bq >> 3, tid = threadIdx.x;
  int wave = tid >> 6, lane = tid & 63;
  __shared__ float qxw[CC], qxa[CC], sxg[CC];
  for (int c = tid; c < CC; c += 256){
    float qv = q[bq*CC + c];
    float kl = kv[((size_t)b*TT + (TT-1))*CC + c];
    xrw[bq*CC + c] = kl + (qv - kl)*x_r[c];
    sxg[c] = kl + (qv - kl)*x_g[c];
    qxw[c] = qv*x_w[c];
    qxa[c] = qv*x_a[c];
  }
  __syncthreads();
  for (int dot = wave; dot < 160; dot += 4){
    const float* buf; const float* W; int ld, dd;
    if (dot < 32)      { buf = qxw; W = w1; ld = 32; dd = dot; }
    else if (dot < 64) { buf = qxa; W = a1; ld = 32; dd = dot-32; }
    else               { buf = sxg; W = g1; ld = 96; dd = dot-64; }
    float s = 0.f;
    #pragma unroll
    for (int m = 0; m < 8; m++){
      int c = m*64 + lane;
      s = fmaf(buf[c], W[c*ld + dd], s);
    }
    s = wsum(s);
    if (lane == 0){
      if (dot < 32)      Qw[bq*32 + dd] = s;
      else if (dot < 64) Qa[bq*32 + dd] = s;
      else               ghw[bq*96 + dd] = sigm(s);
    }
  }
}

// ---------------------------------------------------------------------------
// k_rg: rrow[bq,co] = xr[bq,:]@Wr[:,co], grow[bq,co] = gh[bq,:]@g2[:,co]
// grid (8 co-chunks, 32 bq). Coalesced Wr reads, LDS reduction.
// ---------------------------------------------------------------------------
__global__ __launch_bounds__(256) void k_rg(
  const float* __restrict__ xrw, const float* __restrict__ ghw,
  const float* __restrict__ Wr, const float* __restrict__ g2,
  float* __restrict__ rrow, float* __restrict__ grow)
{
  int bq = blockIdx.y; int co0 = blockIdx.x*64;
  int tid = threadIdx.x, tx = tid & 63, ty = tid >> 6;
  __shared__ float sxr[CC];
  __shared__ float sgh[96];
  __shared__ float red[4][64];
  sxr[tid]     = xrw[bq*CC + tid];
  sxr[tid+256] = xrw[bq*CC + tid + 256];
  if (tid < 96) sgh[tid] = ghw[bq*96 + tid];
  __syncthreads();
  float p = 0.f;
  for (int i = 0; i < 128; i++){
    int c = ty*128 + i;
    p = fmaf(sxr[c], Wr[(size_t)c*CC + co0 + tx], p);
  }
  red[ty][tx] = p;
  float pg = 0.f;
  for (int d = ty*24; d < ty*24 + 24; d++)
    pg = fmaf(sgh[d], g2[(size_t)d*CC + co0 + tx], pg);
  __syncthreads();
  if (ty == 0)
    rrow[bq*CC + co0 + tx] = (red[0][tx]+red[1][tx])+(red[2][tx]+red[3][tx]);
  __syncthreads();
  red[ty][tx] = pg;
  __syncthreads();
  if (ty == 0)
    grow[bq*CC + co0 + tx] = (red[0][tx]+red[1][tx])+(red[2][tx]+red[3][tx]);
}

// ---------------------------------------------------------------------------
// K1: per-(b,t) (2048 rows — xk/xv/sv/P_w/P_a depend only on b, not bq)
// dots wave-parallel (wsum).
// ---------------------------------------------------------------------------
__global__ __launch_bounds__(256) void k_perbt(
  const float* __restrict__ kv,
  const float* __restrict__ x_k, const float* __restrict__ x_v,
  const float* __restrict__ x_w, const float* __restrict__ x_a,
  const float* __restrict__ w1, const float* __restrict__ a1,
  const float* __restrict__ v0, const float* __restrict__ v1,
  const float* __restrict__ v2,
  float* __restrict__ xk, float* __restrict__ xv,
  float* __restrict__ Pw, float* __restrict__ Pa,
  float* __restrict__ svv)
{
  int bt = blockIdx.x; int t = bt & (TT-1); int tid = threadIdx.x;
  int wave = tid >> 6, lane = tid & 63;
  const float* cur = kv + (size_t)bt*CC;
  __shared__ float sxv[CC], sxw[CC], sxa[CC], hv[32];
  for (int c = tid; c < CC; c += 256){
    float x  = cur[c];
    float sh = t ? cur[c - CC] : 0.f;   // token shift within same b
    float d  = sh - x;
    float xkc = x + d*x_k[c];
    float xvc = x + d*x_v[c];
    xk[(size_t)bt*CC + c] = xkc;
    xv[(size_t)bt*CC + c] = xvc;
    sxv[c] = xvc;
    sxw[c] = x*(1.f - x_w[c]);
    sxa[c] = x*(1.f - x_a[c]);
  }
  __syncthreads();
  for (int dot = wave; dot < 96; dot += 4){
    const float* buf = (dot < 32) ? sxw : (dot < 64) ? sxa : sxv;
    const float* W   = (dot < 32) ? w1  : (dot < 64) ? a1  : v1;
    int dd = dot & 31;
    float s = 0.f;
    #pragma unroll
    for (int m = 0; m < 8; m++){
      int c = m*64 + lane;
      s = fmaf(buf[c], W[c*32 + dd], s);
    }
    s = wsum(s);
    if (lane == 0){
      if (dot < 32)      Pw[bt*32 + dd] = s;
      else if (dot < 64) Pa[bt*32 + dd] = s;
      else               hv[dd] = s;
    }
  }
  __syncthreads();
  for (int c = tid; c < CC; c += 256){
    float s = 0.f;
    #pragma unroll
    for (int d = 0; d < 32; d++) s += hv[d]*v2[d*CC + c];
    svv[(size_t)bt*CC + c] = sigm(v0[c] + s);
  }
}

// ---------------------------------------------------------------------------
// Tiled fp32 GEMM: C[2048x512] = A[2048x512] @ W[512x512]. 64x64 tile, 4x4/thread.
// ---------------------------------------------------------------------------
__global__ __launch_bounds__(256) void gemm_2048_512(
  const float* __restrict__ A, const float* __restrict__ W, float* __restrict__ Co)
{
  __shared__ float As[32][68];   // [k][m], padded
  __shared__ float Bs[32][64];   // [k][n]
  int tid = threadIdx.x;
  int tx = tid & 15, ty = tid >> 4;
  int m0 = blockIdx.y*64, n0 = blockIdx.x*64;
  float acc[4][4];
  #pragma unroll
  for (int i=0;i<4;i++)
    #pragma unroll
    for (int j=0;j<4;j++) acc[i][j]=0.f;

  for (int k0 = 0; k0 < 512; k0 += 32){
    #pragma unroll
    for (int i = 0; i < 8; i++){
      int e = tid + i*256;
      int kk = e & 31, m = e >> 5;
      As[kk][m] = A[(size_t)(m0+m)*512 + k0 + kk];
    }
    #pragma unroll
    for (int i = 0; i < 8; i++){
      int e = tid + i*256;
      int n = e & 63, kk = e >> 6;
      Bs[kk][n] = W[(size_t)(k0+kk)*512 + n0 + n];
    }
    __syncthreads();
    #pragma unroll
    for (int kk = 0; kk < 32; kk++){
      float a4[4], b4[4];
      #pragma unroll
      for (int i=0;i<4;i++) a4[i] = As[kk][ty*4+i];
      #pragma unroll
      for (int j=0;j<4;j++) b4[j] = Bs[kk][tx*4+j];
      #pragma unroll
      for (int i=0;i<4;i++)
        #pragma unroll
        for (int j=0;j<4;j++) acc[i][j] += a4[i]*b4[j];
    }
    __syncthreads();
  }
  #pragma unroll
  for (int i=0;i<4;i++)
    #pragma unroll
    for (int j=0;j<4;j++)
      Co[(size_t)(m0+ty*4+i)*512 + n0 + tx*4 + j] = acc[i][j];
}

// ---------------------------------------------------------------------------
// K1b: kk = normalize_per_head(k * k_k)  (per-b, 2048 rows)
// ---------------------------------------------------------------------------
__global__ __launch_bounds__(512) void k_kk(
  const float* __restrict__ kg, const float* __restrict__ k_k,
  float* __restrict__ kkg)
{
  int bt = blockIdx.x, tid = threadIdx.x;     // tid = c; head = tid>>6 (wave-aligned)
  float v = kg[(size_t)bt*CC + tid]*k_k[tid];
  float ss = wsum(v*v);
  float nrm = fmaxf(sqrtf(ss), 1e-12f);
  kkg[(size_t)bt*CC + tid] = v/nrm;
}

// ---------------------------------------------------------------------------
// K2a: th = tanh(Pw+Qw), al = Pa+Qa   (16384 x 32 each)
// ---------------------------------------------------------------------------
__global__ __launch_bounds__(256) void k_thal(
  const float* __restrict__ Pw, const float* __restrict__ Pa,
  const float* __restrict__ Qw, const float* __restrict__ Qa,
  float* __restrict__ th, float* __restrict__ al)
{
  int idx = blockIdx.x*256 + threadIdx.x;       // [0, 524288)
  int bqt = idx >> 5, d = idx & 31;
  int bq = bqt >> 9, t = bqt & (TT-1), b = bq >> 3;
  int pidx = ((b << 9) | t)*32 + d;
  th[idx] = tanhf(Pw[pidx] + Qw[bq*32 + d]);
  al[idx] = Pa[pidx] + Qa[bq*32 + d];
}

// ---------------------------------------------------------------------------
// K2: per (bq,t,c): decay w, k_final, b_vec = kk*a
// ---------------------------------------------------------------------------
__global__ __launch_bounds__(256) void k_wkb(
  const float* __restrict__ th, const float* __restrict__ al,
  const float* __restrict__ w2, const float* __restrict__ a2,
  const float* __restrict__ w0, const float* __restrict__ a0,
  const float* __restrict__ k_a, const float* __restrict__ kg,
  const float* __restrict__ kkg,
  float* __restrict__ wS, float* __restrict__ kS, float* __restrict__ bS)
{
  int bqt = blockIdx.x; int bq = bqt >> 9, t = bqt & (TT-1), b = bq >> 3;
  size_t bt = (size_t)((b << 9) | t);
  const float* thp = th + (size_t)bqt*32;
  const float* alp = al + (size_t)bqt*32;
  float thr[32], alr[32];
  #pragma unroll
  for (int d = 0; d < 32; d++){ thr[d] = thp[d]; alr[d] = alp[d]; }
  #pragma unroll
  for (int cc = 0; cc < 2; cc++){
    int c = threadIdx.x + cc*256;
    float w0a=0,w1a=0,a0a=0,a1a=0;
    #pragma unroll
    for (int d = 0; d < 32; d += 2){
      w0a += thr[d]  *w2[d*CC + c];
      w1a += thr[d+1]*w2[(d+1)*CC + c];
      a0a += alr[d]  *a2[d*CC + c];
      a1a += alr[d+1]*a2[(d+1)*CC + c];
    }
    float a_sig = sigm(a0[c] + a0a + a1a);
    float wdec  = __expf(-0.60653066f * sigm(w0[c] + w0a + w1a));
    float kvv = kg[bt*CC + c];
    float kkv = kkg[bt*CC + c];
    size_t o = (size_t)bqt*CC + c;
    wS[o] = wdec;
    kS[o] = kvv*(1.f + (a_sig - 1.f)*k_a[c]);
    bS[o] = kkv*a_sig;
  }
}

// ---------------------------------------------------------------------------
// K3: scan, 4 waves per (bq,h). Wave w owns state columns [16w,16w+16);
// lane = row i. Per step: one barrier; sa via LDS partial exchange; staged
// vectors {w,k,b,a_next} packed float4/column in a 3-deep rotating LDS buffer
// fed by a 2-step register pipeline of coalesced global loads.
// Pipeline invariant entering iter t: Pold=data(t+1), Pnew=data(t+2);
// in-loop reload fetches data(t+3) (w/k/b@t+3, kk@t+4).  [R3 bug: was t+2/t+3]
// ---------------------------------------------------------------------------
__global__ __launch_bounds__(256, 1) void k_scan(
  const float* __restrict__ wv, const float* __restrict__ kf,
  const float* __restrict__ bv, const float* __restrict__ kkg,
  const float* __restrict__ vpre, const float* __restrict__ svv,
  const float* __restrict__ vfirst,
  const float* __restrict__ rrow, const float* __restrict__ grow,
  const float* __restrict__ r_k, const float* __restrict__ ln_w,
  const float* __restrict__ ln_b, float* __restrict__ xo)
{
  __shared__ __align__(16) float stage[3][256];  // col j: [4j..4j+3]={w_t,k_t,b_t,kk_{t+1}}
  __shared__ __align__(16) float psa[2][256];    // [i*4 + wave]
  __shared__ __align__(16) float pout[256];
  __shared__ float vbuf[2][64];
  int blk = blockIdx.x; int bq = blk >> 3, h = blk & 7, b = bq >> 3;
  int tid = threadIdx.x; int wave = tid >> 6; int lane = tid & 63;
  size_t cb_bq = (size_t)bq*TT*CC + h*NN;   // + t*CC + j
  size_t cb_b  = (size_t)b*TT*CC + h*NN;

  float st[16];
  #pragma unroll
  for (int jj = 0; jj < 16; jj++) st[jj] = 0.f;

  psa[0][tid] = 0.f;

  // direct stage for t=0: {w0,k0,b0,kk_1}
  {
    float v;
    if      (wave == 0) v = wv [cb_bq + lane];
    else if (wave == 1) v = kf [cb_bq + lane];
    else if (wave == 2) v = bv [cb_bq + lane];
    else                v = kkg[cb_b + CC + lane];
    stage[0][lane*4 + wave] = v;
  }
  // register pipeline: Pold = data(1), Pnew = data(2)
  float Pold, Pnew;
  if      (wave == 0) Pold = wv [cb_bq + CC + lane];
  else if (wave == 1) Pold = kf [cb_bq + CC + lane];
  else if (wave == 2) Pold = bv [cb_bq + CC + lane];
  else                Pold = kkg[cb_b + 2*CC + lane];
  if      (wave == 0) Pnew = wv [cb_bq + 2*CC + lane];
  else if (wave == 1) Pnew = kf [cb_bq + 2*CC + lane];
  else if (wave == 2) Pnew = bv [cb_bq + 2*CC + lane];
  else                Pnew = kkg[cb_b + 3*CC + lane];

  // v pipeline (wave 0 only): vbuf[t&1][i] = v_t[i]
  float vpc=0.f, svc=0.f, vfc=0.f, vpn=0.f, svn=0.f, vfn=0.f;
  if (wave == 0){
    float vp0 = vpre[cb_b + lane], sv0 = svv[cb_b + lane], vf0 = vfirst[cb_bq + lane];
    vbuf[0][lane] = vp0 + (vf0 - vp0)*sv0;
    vpc = vpre[cb_b + CC + lane]; svc = svv[cb_b + CC + lane]; vfc = vfirst[cb_bq + CC + lane];
    vpn = vpre[cb_b + 2*CC + lane]; svn = svv[cb_b + 2*CC + lane]; vfn = vfirst[cb_bq + 2*CC + lane];
  }
  __syncthreads();

  float v_i = 0.f;
  for (int t = 0; t < TT; t++){
    // write pending (data for t+1) into stage[(t+1)%3]
    stage[(t+1)%3][lane*4 + wave] = Pold;
    Pold = Pnew;
    {
      int tl = (t+3 < TT) ? t+3 : TT-1;     // data(t+3): w/k/b @ t+3
      int ta = (t+4 < TT) ? t+4 : TT-1;     // data(t+3): kk @ t+4
      if      (wave == 0) Pnew = wv [cb_bq + (size_t)tl*CC + lane];
      else if (wave == 1) Pnew = kf [cb_bq + (size_t)tl*CC + lane];
      else if (wave == 2) Pnew = bv [cb_bq + (size_t)tl*CC + lane];
      else                Pnew = kkg[cb_b + (size_t)ta*CC + lane];
    }
    if (wave == 0){
      vbuf[(t+1)&1][lane] = vpc + (vfc - vpc)*svc;   // v_{t+1}
      vpc = vpn; svc = svn; vfc = vfn;
      int tl = (t+3 < TT) ? t+3 : TT-1;              // v data @ t+3
      vpn = vpre[cb_b + (size_t)tl*CC + lane];
      svn = svv [cb_b + (size_t)tl*CC + lane];
      vfn = vfirst[cb_bq + (size_t)tl*CC + lane];
    }
    // sa from the 4 partials of step t
    float4 ps = ((const float4*)psa[t&1])[lane];
    float sa = -((ps.x + ps.y) + (ps.z + ps.w));
    v_i = vbuf[t&1][lane];
    const float4* cv = (const float4*)stage[t%3];
    float pn = 0.f;
    #pragma unroll
    for (int jj = 0; jj < 16; jj++){
      float4 c = cv[wave*16 + jj];
      st[jj] = fmaf(st[jj], c.x, fmaf(sa, c.z, v_i*c.y));
      pn = fmaf(st[jj], c.w, pn);      // partial S_t · kk_{t+1}
    }
    psa[(t+1)&1][lane*4 + wave] = pn;
    __syncthreads();
  }

  // epilogue: out_i = sum_j S[i,j] r[j]  (partials over own columns)
  {
    const float* rp = rrow + (size_t)bq*CC + h*NN;
    float po = 0.f;
    #pragma unroll
    for (int jj = 0; jj < 16; jj++) po = fmaf(st[jj], rp[wave*16 + jj], po);
    pout[lane*4 + wave] = po;
  }
  __syncthreads();
  if (wave == 0){
    float4 p4 = ((const float4*)pout)[lane];
    float out = (p4.x + p4.y) + (p4.z + p4.w);
    float mean = wsum(out) * (1.f/NN);
    float dv = out - mean;
    float var = wsum(dv*dv) * (1.f/NN);
    float yn = dv * rsqrtf(var + 6.4e-4f);   // GN_EPS = 1e-5*64
    int c = h*NN + lane;
    float y2 = yn * ln_w[c] + ln_b[c];
    float kl = kf[cb_bq + (size_t)(TT-1)*CC + lane];
    float rl = rrow[(size_t)bq*CC + h*NN + lane];
    float rk = wsum(rl*kl*r_k[c]);
    float res = (y2 + rk*v_i) * grow[(size_t)bq*CC + c];
    xo[bq*CC + c] = res;
  }
}

// ---------------------------------------------------------------------------
// K4: out[bq,co] = xo[bq,:] @ Wo[:,co]   grid (8 co-chunks, 32 bq)
// ---------------------------------------------------------------------------
__global__ __launch_bounds__(256) void k_out(
  const float* __restrict__ xo, const float* __restrict__ Wo,
  float* __restrict__ outp)
{
  int bq = blockIdx.y; int co0 = blockIdx.x*64;
  int tid = threadIdx.x, tx = tid & 63, ty = tid >> 6;
  __shared__ float row[CC];
  __shared__ float red[4][64];
  row[tid]     = xo[bq*CC + tid];
  row[tid+256] = xo[bq*CC + tid + 256];
  __syncthreads();
  float p = 0.f;
  for (int i = 0; i < 128; i++){
    int c = ty*128 + i;
    p = fmaf(row[c], Wo[(size_t)c*CC + co0 + tx], p);
  }
  red[ty][tx] = p;
  __syncthreads();
  if (ty == 0)
    outp[bq*CC + co0 + tx] = (red[0][tx]+red[1][tx])+(red[2][tx]+red[3][tx]);
}

// ---------------------------------------------------------------------------
extern "C" void kernel_launch(void* const* d_in, const int* in_sizes, int n_in,
                              void* d_out, int out_size, void* d_ws, size_t ws_size,
                              hipStream_t stream)
{
  const float* q   = (const float*)d_in[0];
  const float* kv  = (const float*)d_in[1];
  const float* vf  = (const float*)d_in[2];
  const float* x_r = (const float*)d_in[3];
  const float* x_w = (const float*)d_in[4];
  const float* x_k = (const float*)d_in[5];
  const float* x_v = (const float*)d_in[6];
  const float* x_a = (const float*)d_in[7];
  const float* x_g = (const float*)d_in[8];
  const float* w0  = (const float*)d_in[9];
  const float* w1  = (const float*)d_in[10];
  const float* w2  = (const float*)d_in[11];
  const float* a0  = (const float*)d_in[12];
  const float* a1  = (const float*)d_in[13];
  const float* a2  = (const float*)d_in[14];
  const float* v0  = (const float*)d_in[15];
  const float* v1  = (const float*)d_in[16];
  const float* v2  = (const float*)d_in[17];
  const float* g1  = (const float*)d_in[18];
  const float* g2  = (const float*)d_in[19];
  const float* k_k = (const float*)d_in[20];
  const float* k_a = (const float*)d_in[21];
  const float* r_k = (const float*)d_in[22];
  const float* Wr  = (const float*)d_in[23];
  const float* Wk  = (const float*)d_in[24];
  const float* Wv  = (const float*)d_in[25];
  const float* Wo  = (const float*)d_in[26];
  const float* lnw = (const float*)d_in[27];
  const float* lnb = (const float*)d_in[28];
  float* outp = (float*)d_out;
  float* ws = (float*)d_ws;

  // workspace layout (floats)
  float* xk = ws + 0;         // 4*512*512
  float* xv = ws + 1048576;
  float* kg = ws + 2097152;   // k
  float* vp = ws + 3145728;   // v_pre
  float* sv = ws + 4194304;   // sigmoid lerp factor
  float* kk = ws + 5242880;   // normalized kk
  float* Pw = ws + 6291456;   // 4*512*32
  float* Pa = ws + 6356992;
  float* Qw = ws + 6422528;   // 32*32
  float* Qa = ws + 6423552;
  float* th = ws + 6424576;   // 32*512*32
  float* al = ws + 6948864;
  float* rr = ws + 7473152;   // 32*512
  float* gr = ws + 7489536;
  float* xo = ws + 7505920;
  float* wS = ws + 7522304;   // 32*512*512 decay
  float* kS = ws + 15910912;  // k_final
  float* bS = ws + 24299520;  // kk*a
  float* xrw = ws + 32688128; // 32*512
  float* ghw = ws + 32704512; // 32*96

  // v_first passthrough (tuple output #2)
  hipMemcpyAsync(outp + BQ*CC, vf,
                 (size_t)BQ*TT*CC*sizeof(float), hipMemcpyDeviceToDevice, stream);

  k_prep<<<32, 256, 0, stream>>>(q, kv, x_r, x_w, x_a, x_g, w1, a1, g1,
                                 Qw, Qa, ghw, xrw);
  k_rg<<<dim3(8, 32), 256, 0, stream>>>(xrw, ghw, Wr, g2, rr, gr);
  k_perbt<<<NB*TT, 256, 0, stream>>>(kv, x_k, x_v, x_w, x_a, w1, a1, v0, v1, v2,
                                     xk, xv, Pw, Pa, sv);
  gemm_2048_512<<<dim3(8, 32), 256, 0, stream>>>(xk, Wk, kg);
  gemm_2048_512<<<dim3(8, 32), 256, 0, stream>>>(xv, Wv, vp);
  k_kk<<<NB*TT, 512, 0, stream>>>(kg, k_k, kk);
  k_thal<<<2048, 256, 0, stream>>>(Pw, Pa, Qw, Qa, th, al);
  k_wkb<<<BQ*TT, 256, 0, stream>>>(th, al, w2, a2, w0, a0, k_a, kg, kk, wS, kS, bS);
  k_scan<<<BQ*HH, 256, 0, stream>>>(wS, kS, bS, kk, vp, sv, vf, rr, gr, r_k,
                                    lnw, lnb, xo);
  k_out<<<dim3(8, 32), 256, 0, stream>>>(xo, Wo, outp);
}

// Round 5
// 1053.342 us; speedup vs baseline: 1.9068x; 1.0560x over previous
//
#include <hip/hip_runtime.h>
#include <cstdint>

// Problem constants
#define TT 512   // KVLEN
#define CC 512   // C
#define HH 8     // heads
#define NN 64    // head dim
#define BQ 32    // BATCH*QLEN
#define NB 4     // BATCH

__device__ __forceinline__ float sigm(float x){ return 1.f/(1.f+__expf(-x)); }

__device__ __forceinline__ float wsum(float x){
  #pragma unroll
  for (int o=32;o;o>>=1) x += __shfl_xor(x, o, 64);
  return x;
}

// LDS-only barrier: does NOT drain vmcnt, so global prefetch loads stay in
// flight across steps (the __syncthreads() vmcnt(0) drain was the k_scan
// bottleneck: ~900 cy exposed per step).
#define LDS_BARRIER() asm volatile("s_waitcnt lgkmcnt(0)\n\ts_barrier" ::: "memory")

// ---------------------------------------------------------------------------
// k_prep: per-bq small dots (32 blocks): Qw[bq,32], Qa[bq,32], gh[bq,96],
// and xr row -> workspace. Each dot is one wave: 8 elems/lane + wsum.
// ---------------------------------------------------------------------------
__global__ __launch_bounds__(256) void k_prep(
  const float* __restrict__ q, const float* __restrict__ kv,
  const float* __restrict__ x_r, const float* __restrict__ x_w,
  const float* __restrict__ x_a, const float* __restrict__ x_g,
  const float* __restrict__ w1, const float* __restrict__ a1,
  const float* __restrict__ g1,
  float* __restrict__ Qw, float* __restrict__ Qa,
  float* __restrict__ ghw, float* __restrict__ xrw)
{
  int bq = blockIdx.x, b = bq >> 3, tid = threadIdx.x;
  int wave = tid >> 6, lane = tid & 63;
  __shared__ float qxw[CC], qxa[CC], sxg[CC];
  for (int c = tid; c < CC; c += 256){
    float qv = q[bq*CC + c];
    float kl = kv[((size_t)b*TT + (TT-1))*CC + c];
    xrw[bq*CC + c] = kl + (qv - kl)*x_r[c];
    sxg[c] = kl + (qv - kl)*x_g[c];
    qxw[c] = qv*x_w[c];
    qxa[c] = qv*x_a[c];
  }
  __syncthreads();
  for (int dot = wave; dot < 160; dot += 4){
    const float* buf; const float* W; int ld, dd;
    if (dot < 32)      { buf = qxw; W = w1; ld = 32; dd = dot; }
    else if (dot < 64) { buf = qxa; W = a1; ld = 32; dd = dot-32; }
    else               { buf = sxg; W = g1; ld = 96; dd = dot-64; }
    float s = 0.f;
    #pragma unroll
    for (int m = 0; m < 8; m++){
      int c = m*64 + lane;
      s = fmaf(buf[c], W[c*ld + dd], s);
    }
    s = wsum(s);
    if (lane == 0){
      if (dot < 32)      Qw[bq*32 + dd] = s;
      else if (dot < 64) Qa[bq*32 + dd] = s;
      else               ghw[bq*96 + dd] = sigm(s);
    }
  }
}

// ---------------------------------------------------------------------------
// k_rg: rrow[bq,co] = xr[bq,:]@Wr[:,co], grow[bq,co] = gh[bq,:]@g2[:,co]
// ---------------------------------------------------------------------------
__global__ __launch_bounds__(256) void k_rg(
  const float* __restrict__ xrw, const float* __restrict__ ghw,
  const float* __restrict__ Wr, const float* __restrict__ g2,
  float* __restrict__ rrow, float* __restrict__ grow)
{
  int bq = blockIdx.y; int co0 = blockIdx.x*64;
  int tid = threadIdx.x, tx = tid & 63, ty = tid >> 6;
  __shared__ float sxr[CC];
  __shared__ float sgh[96];
  __shared__ float red[4][64];
  sxr[tid]     = xrw[bq*CC + tid];
  sxr[tid+256] = xrw[bq*CC + tid + 256];
  if (tid < 96) sgh[tid] = ghw[bq*96 + tid];
  __syncthreads();
  float p = 0.f;
  for (int i = 0; i < 128; i++){
    int c = ty*128 + i;
    p = fmaf(sxr[c], Wr[(size_t)c*CC + co0 + tx], p);
  }
  red[ty][tx] = p;
  float pg = 0.f;
  for (int d = ty*24; d < ty*24 + 24; d++)
    pg = fmaf(sgh[d], g2[(size_t)d*CC + co0 + tx], pg);
  __syncthreads();
  if (ty == 0)
    rrow[bq*CC + co0 + tx] = (red[0][tx]+red[1][tx])+(red[2][tx]+red[3][tx]);
  __syncthreads();
  red[ty][tx] = pg;
  __syncthreads();
  if (ty == 0)
    grow[bq*CC + co0 + tx] = (red[0][tx]+red[1][tx])+(red[2][tx]+red[3][tx]);
}

// ---------------------------------------------------------------------------
// K1: per-(b,t) (2048 rows)
// ---------------------------------------------------------------------------
__global__ __launch_bounds__(256) void k_perbt(
  const float* __restrict__ kv,
  const float* __restrict__ x_k, const float* __restrict__ x_v,
  const float* __restrict__ x_w, const float* __restrict__ x_a,
  const float* __restrict__ w1, const float* __restrict__ a1,
  const float* __restrict__ v0, const float* __restrict__ v1,
  const float* __restrict__ v2,
  float* __restrict__ xk, float* __restrict__ xv,
  float* __restrict__ Pw, float* __restrict__ Pa,
  float* __restrict__ svv)
{
  int bt = blockIdx.x; int t = bt & (TT-1); int tid = threadIdx.x;
  int wave = tid >> 6, lane = tid & 63;
  const float* cur = kv + (size_t)bt*CC;
  __shared__ float sxv[CC], sxw[CC], sxa[CC], hv[32];
  for (int c = tid; c < CC; c += 256){
    float x  = cur[c];
    float sh = t ? cur[c - CC] : 0.f;
    float d  = sh - x;
    float xkc = x + d*x_k[c];
    float xvc = x + d*x_v[c];
    xk[(size_t)bt*CC + c] = xkc;
    xv[(size_t)bt*CC + c] = xvc;
    sxv[c] = xvc;
    sxw[c] = x*(1.f - x_w[c]);
    sxa[c] = x*(1.f - x_a[c]);
  }
  __syncthreads();
  for (int dot = wave; dot < 96; dot += 4){
    const float* buf = (dot < 32) ? sxw : (dot < 64) ? sxa : sxv;
    const float* W   = (dot < 32) ? w1  : (dot < 64) ? a1  : v1;
    int dd = dot & 31;
    float s = 0.f;
    #pragma unroll
    for (int m = 0; m < 8; m++){
      int c = m*64 + lane;
      s = fmaf(buf[c], W[c*32 + dd], s);
    }
    s = wsum(s);
    if (lane == 0){
      if (dot < 32)      Pw[bt*32 + dd] = s;
      else if (dot < 64) Pa[bt*32 + dd] = s;
      else               hv[dd] = s;
    }
  }
  __syncthreads();
  for (int c = tid; c < CC; c += 256){
    float s = 0.f;
    #pragma unroll
    for (int d = 0; d < 32; d++) s += hv[d]*v2[d*CC + c];
    svv[(size_t)bt*CC + c] = sigm(v0[c] + s);
  }
}

// ---------------------------------------------------------------------------
// Tiled fp32 GEMM: C[2048x512] = A[2048x512] @ W[512x512]. 64x64 tile.
// ---------------------------------------------------------------------------
__global__ __launch_bounds__(256) void gemm_2048_512(
  const float* __restrict__ A, const float* __restrict__ W, float* __restrict__ Co)
{
  __shared__ float As[32][68];
  __shared__ float Bs[32][64];
  int tid = threadIdx.x;
  int tx = tid & 15, ty = tid >> 4;
  int m0 = blockIdx.y*64, n0 = blockIdx.x*64;
  float acc[4][4];
  #pragma unroll
  for (int i=0;i<4;i++)
    #pragma unroll
    for (int j=0;j<4;j++) acc[i][j]=0.f;

  for (int k0 = 0; k0 < 512; k0 += 32){
    #pragma unroll
    for (int i = 0; i < 8; i++){
      int e = tid + i*256;
      int kk = e & 31, m = e >> 5;
      As[kk][m] = A[(size_t)(m0+m)*512 + k0 + kk];
    }
    #pragma unroll
    for (int i = 0; i < 8; i++){
      int e = tid + i*256;
      int n = e & 63, kk = e >> 6;
      Bs[kk][n] = W[(size_t)(k0+kk)*512 + n0 + n];
    }
    __syncthreads();
    #pragma unroll
    for (int kk = 0; kk < 32; kk++){
      float a4[4], b4[4];
      #pragma unroll
      for (int i=0;i<4;i++) a4[i] = As[kk][ty*4+i];
      #pragma unroll
      for (int j=0;j<4;j++) b4[j] = Bs[kk][tx*4+j];
      #pragma unroll
      for (int i=0;i<4;i++)
        #pragma unroll
        for (int j=0;j<4;j++) acc[i][j] += a4[i]*b4[j];
    }
    __syncthreads();
  }
  #pragma unroll
  for (int i=0;i<4;i++)
    #pragma unroll
    for (int j=0;j<4;j++)
      Co[(size_t)(m0+ty*4+i)*512 + n0 + tx*4 + j] = acc[i][j];
}

// ---------------------------------------------------------------------------
// K1b: kk = normalize_per_head(k * k_k)
// ---------------------------------------------------------------------------
__global__ __launch_bounds__(512) void k_kk(
  const float* __restrict__ kg, const float* __restrict__ k_k,
  float* __restrict__ kkg)
{
  int bt = blockIdx.x, tid = threadIdx.x;
  float v = kg[(size_t)bt*CC + tid]*k_k[tid];
  float ss = wsum(v*v);
  float nrm = fmaxf(sqrtf(ss), 1e-12f);
  kkg[(size_t)bt*CC + tid] = v/nrm;
}

// ---------------------------------------------------------------------------
// K2: per (bq,t,c): decay w, k_final, b_vec = kk*a.  4 rows per block;
// th/al staged in LDS (tanh fused here — k_thal removed); w2/a2 columns held
// in registers across the 4 rows (4x less L2 weight traffic).
// ---------------------------------------------------------------------------
__global__ __launch_bounds__(256) void k_wkb(
  const float* __restrict__ Pw, const float* __restrict__ Pa,
  const float* __restrict__ Qw, const float* __restrict__ Qa,
  const float* __restrict__ w2, const float* __restrict__ a2,
  const float* __restrict__ w0, const float* __restrict__ a0,
  const float* __restrict__ k_a, const float* __restrict__ kg,
  const float* __restrict__ kkg,
  float* __restrict__ wS, float* __restrict__ kS, float* __restrict__ bS)
{
  int bqt0 = blockIdx.x*4;           // 4 consecutive t within one bq
  int bq = bqt0 >> 9, t0 = bqt0 & (TT-1), b = bq >> 3;
  int tid = threadIdx.x;
  __shared__ float sth[4][32], sal[4][32];
  {
    int g = (tid >> 5) & 3, d = tid & 31;
    int pidx = ((b << 9) | (t0 + g))*32 + d;
    if (tid < 128) sth[g][d] = tanhf(Pw[pidx] + Qw[bq*32 + d]);
    else           sal[g][d] = Pa[pidx] + Qa[bq*32 + d];
  }
  __syncthreads();
  #pragma unroll
  for (int cc = 0; cc < 2; cc++){
    int c = tid + cc*256;
    float wreg[32], areg[32];
    #pragma unroll
    for (int d = 0; d < 32; d++){ wreg[d] = w2[d*CC + c]; areg[d] = a2[d*CC + c]; }
    float w0c = w0[c], a0c = a0[c], kac = k_a[c];
    #pragma unroll
    for (int g = 0; g < 4; g++){
      float wa = 0.f, aa = 0.f;
      #pragma unroll
      for (int d = 0; d < 32; d++){
        wa = fmaf(sth[g][d], wreg[d], wa);
        aa = fmaf(sal[g][d], areg[d], aa);
      }
      float a_sig = sigm(a0c + aa);
      float wdec  = __expf(-0.60653066f * sigm(w0c + wa));
      size_t bt = (size_t)((b << 9) | (t0 + g));
      size_t o  = (size_t)(bqt0 + g)*CC + c;
      float kvv = kg[bt*CC + c];
      float kkv = kkg[bt*CC + c];
      wS[o] = wdec;
      kS[o] = kvv*(1.f + (a_sig - 1.f)*kac);
      bS[o] = kkv*a_sig;
    }
  }
}

// ---------------------------------------------------------------------------
// K3: scan, 4 waves per (bq,h). Wave w owns state columns [16w,16w+16);
// lane = row i.  Staging role: comp=lane&3 (0=w,1=k,2=b,3=kk_next),
// col=wave*16+(lane>>2) -> LDS write index 64*wave+lane = 4*col+comp (linear,
// conflict-free).  Column reads are natural-order float4 broadcasts.
// Barriers are LDS-only (no vmcnt drain) so the depth-2 register prefetch
// pipeline genuinely covers global latency.
// ---------------------------------------------------------------------------
__global__ __launch_bounds__(256, 1) void k_scan(
  const float* __restrict__ wv, const float* __restrict__ kf,
  const float* __restrict__ bv, const float* __restrict__ kkg,
  const float* __restrict__ vpre, const float* __restrict__ svv,
  const float* __restrict__ vfirst,
  const float* __restrict__ rrow, const float* __restrict__ grow,
  const float* __restrict__ r_k, const float* __restrict__ ln_w,
  const float* __restrict__ ln_b, float* __restrict__ xo)
{
  __shared__ __align__(16) float stage[3][256];  // dword 4*col+comp
  __shared__ float psa[2][256];                  // [wave*64 + row]
  __shared__ float pout[256];
  __shared__ float vbuf[2][64];
  int blk = blockIdx.x; int bq = blk >> 3, h = blk & 7, b = bq >> 3;
  int tid = threadIdx.x; int wave = tid >> 6; int lane = tid & 63;
  size_t cb_bq = (size_t)bq*TT*CC + h*NN;
  size_t cb_b  = (size_t)b*TT*CC + h*NN;

  // staging role
  int comp = lane & 3, col = wave*16 + (lane >> 2);
  const float* basep; size_t lbase; int tmaxl;
  if      (comp == 0){ basep = wv;  lbase = cb_bq + col;     tmaxl = TT-1; }
  else if (comp == 1){ basep = kf;  lbase = cb_bq + col;     tmaxl = TT-1; }
  else if (comp == 2){ basep = bv;  lbase = cb_bq + col;     tmaxl = TT-1; }
  else               { basep = kkg; lbase = cb_b + CC + col; tmaxl = TT-2; }

  float st[16];
  #pragma unroll
  for (int jj = 0; jj < 16; jj++) st[jj] = 0.f;
  psa[0][tid] = 0.f;

  // stage t=0 directly; register pipeline Pold=data(1), Pnew=data(2)
  stage[0][tid] = basep[lbase];
  float Pold = basep[lbase + CC];
  float Pnew = basep[lbase + 2*CC];

  // v pipeline (wave 0): vbuf[t&1][i] = v_t[i]
  float vpc=0.f, svc=0.f, vfc=0.f, vpn=0.f, svn=0.f, vfn=0.f;
  if (wave == 0){
    float vp0 = vpre[cb_b + lane], sv0 = svv[cb_b + lane], vf0 = vfirst[cb_bq + lane];
    vbuf[0][lane] = vp0 + (vf0 - vp0)*sv0;
    vpc = vpre[cb_b + CC + lane]; svc = svv[cb_b + CC + lane]; vfc = vfirst[cb_bq + CC + lane];
    vpn = vpre[cb_b + 2*CC + lane]; svn = svv[cb_b + 2*CC + lane]; vfn = vfirst[cb_bq + 2*CC + lane];
  }
  LDS_BARRIER();

  float v_i = 0.f;
  for (int t = 0; t < TT; t++){
    // publish data(t+1); advance pipeline with data(t+3)
    stage[(t+1)%3][tid] = Pold;
    Pold = Pnew;
    {
      int te = t+3; te = (te > tmaxl) ? tmaxl : te;
      Pnew = basep[lbase + (size_t)te*CC];
    }
    if (wave == 0){
      vbuf[(t+1)&1][lane] = vpc + (vfc - vpc)*svc;   // v_{t+1}
      vpc = vpn; svc = svn; vfc = vfn;
      int tv = (t+3 < TT) ? t+3 : TT-1;
      vpn = vpre[cb_b + (size_t)tv*CC + lane];
      svn = svv [cb_b + (size_t)tv*CC + lane];
      vfn = vfirst[cb_bq + (size_t)tv*CC + lane];
    }
    // sa from the 4 partials of step t (stride-1, conflict-free)
    float p0 = psa[t&1][lane],       p1 = psa[t&1][64 + lane];
    float p2 = psa[t&1][128 + lane], p3 = psa[t&1][192 + lane];
    float sa = -((p0 + p1) + (p2 + p3));
    v_i = vbuf[t&1][lane];
    const float4* cv = (const float4*)stage[t%3];
    float pn = 0.f;
    #pragma unroll
    for (int jj = 0; jj < 16; jj++){
      float4 c = cv[wave*16 + jj];           // {w,k,b,kk_next} of column
      st[jj] = fmaf(st[jj], c.x, fmaf(sa, c.z, v_i*c.y));
      pn = fmaf(st[jj], c.w, pn);            // partial S_t · kk_{t+1}
    }
    psa[(t+1)&1][tid] = pn;
    LDS_BARRIER();
  }

  // epilogue: out_i = sum_j S[i,j] r[j]
  {
    const float* rp = rrow + (size_t)bq*CC + h*NN;
    float po = 0.f;
    #pragma unroll
    for (int jj = 0; jj < 16; jj++) po = fmaf(st[jj], rp[wave*16 + jj], po);
    pout[tid] = po;
  }
  __syncthreads();
  if (wave == 0){
    float out = (pout[lane] + pout[64+lane]) + (pout[128+lane] + pout[192+lane]);
    float mean = wsum(out) * (1.f/NN);
    float dv = out - mean;
    float var = wsum(dv*dv) * (1.f/NN);
    float yn = dv * rsqrtf(var + 6.4e-4f);   // GN_EPS = 1e-5*64
    int c = h*NN + lane;
    float y2 = yn * ln_w[c] + ln_b[c];
    float kl = kf[cb_bq + (size_t)(TT-1)*CC + lane];
    float rl = rrow[(size_t)bq*CC + h*NN + lane];
    float rk = wsum(rl*kl*r_k[c]);
    float res = (y2 + rk*v_i) * grow[(size_t)bq*CC + c];
    xo[bq*CC + c] = res;
  }
}

// ---------------------------------------------------------------------------
// K4: out[bq,co] = xo[bq,:] @ Wo[:,co]
// ---------------------------------------------------------------------------
__global__ __launch_bounds__(256) void k_out(
  const float* __restrict__ xo, const float* __restrict__ Wo,
  float* __restrict__ outp)
{
  int bq = blockIdx.y; int co0 = blockIdx.x*64;
  int tid = threadIdx.x, tx = tid & 63, ty = tid >> 6;
  __shared__ float row[CC];
  __shared__ float red[4][64];
  row[tid]     = xo[bq*CC + tid];
  row[tid+256] = xo[bq*CC + tid + 256];
  __syncthreads();
  float p = 0.f;
  for (int i = 0; i < 128; i++){
    int c = ty*128 + i;
    p = fmaf(row[c], Wo[(size_t)c*CC + co0 + tx], p);
  }
  red[ty][tx] = p;
  __syncthreads();
  if (ty == 0)
    outp[bq*CC + co0 + tx] = (red[0][tx]+red[1][tx])+(red[2][tx]+red[3][tx]);
}

// ---------------------------------------------------------------------------
extern "C" void kernel_launch(void* const* d_in, const int* in_sizes, int n_in,
                              void* d_out, int out_size, void* d_ws, size_t ws_size,
                              hipStream_t stream)
{
  const float* q   = (const float*)d_in[0];
  const float* kv  = (const float*)d_in[1];
  const float* vf  = (const float*)d_in[2];
  const float* x_r = (const float*)d_in[3];
  const float* x_w = (const float*)d_in[4];
  const float* x_k = (const float*)d_in[5];
  const float* x_v = (const float*)d_in[6];
  const float* x_a = (const float*)d_in[7];
  const float* x_g = (const float*)d_in[8];
  const float* w0  = (const float*)d_in[9];
  const float* w1  = (const float*)d_in[10];
  const float* w2  = (const float*)d_in[11];
  const float* a0  = (const float*)d_in[12];
  const float* a1  = (const float*)d_in[13];
  const float* a2  = (const float*)d_in[14];
  const float* v0  = (const float*)d_in[15];
  const float* v1  = (const float*)d_in[16];
  const float* v2  = (const float*)d_in[17];
  const float* g1  = (const float*)d_in[18];
  const float* g2  = (const float*)d_in[19];
  const float* k_k = (const float*)d_in[20];
  const float* k_a = (const float*)d_in[21];
  const float* r_k = (const float*)d_in[22];
  const float* Wr  = (const float*)d_in[23];
  const float* Wk  = (const float*)d_in[24];
  const float* Wv  = (const float*)d_in[25];
  const float* Wo  = (const float*)d_in[26];
  const float* lnw = (const float*)d_in[27];
  const float* lnb = (const float*)d_in[28];
  float* outp = (float*)d_out;
  float* ws = (float*)d_ws;

  // workspace layout (floats)
  float* xk = ws + 0;         // 4*512*512
  float* xv = ws + 1048576;
  float* kg = ws + 2097152;   // k
  float* vp = ws + 3145728;   // v_pre
  float* sv = ws + 4194304;   // sigmoid lerp factor
  float* kk = ws + 5242880;   // normalized kk
  float* Pw = ws + 6291456;   // 4*512*32
  float* Pa = ws + 6356992;
  float* Qw = ws + 6422528;   // 32*32
  float* Qa = ws + 6423552;
  float* rr = ws + 7473152;   // 32*512
  float* gr = ws + 7489536;
  float* xo = ws + 7505920;
  float* wS = ws + 7522304;   // 32*512*512 decay
  float* kS = ws + 15910912;  // k_final
  float* bS = ws + 24299520;  // kk*a
  float* xrw = ws + 32688128; // 32*512
  float* ghw = ws + 32704512; // 32*96

  // v_first passthrough (tuple output #2)
  hipMemcpyAsync(outp + BQ*CC, vf,
                 (size_t)BQ*TT*CC*sizeof(float), hipMemcpyDeviceToDevice, stream);

  k_prep<<<32, 256, 0, stream>>>(q, kv, x_r, x_w, x_a, x_g, w1, a1, g1,
                                 Qw, Qa, ghw, xrw);
  k_rg<<<dim3(8, 32), 256, 0, stream>>>(xrw, ghw, Wr, g2, rr, gr);
  k_perbt<<<NB*TT, 256, 0, stream>>>(kv, x_k, x_v, x_w, x_a, w1, a1, v0, v1, v2,
                                     xk, xv, Pw, Pa, sv);
  gemm_2048_512<<<dim3(8, 32), 256, 0, stream>>>(xk, Wk, kg);
  gemm_2048_512<<<dim3(8, 32), 256, 0, stream>>>(xv, Wv, vp);
  k_kk<<<NB*TT, 512, 0, stream>>>(kg, k_k, kk);
  k_wkb<<<BQ*TT/4, 256, 0, stream>>>(Pw, Pa, Qw, Qa, w2, a2, w0, a0, k_a,
                                     kg, kk, wS, kS, bS);
  k_scan<<<BQ*HH, 256, 0, stream>>>(wS, kS, bS, kk, vp, sv, vf, rr, gr, r_k,
                                    lnw, lnb, xo);
  k_out<<<dim3(8, 32), 256, 0, stream>>>(xo, Wo, outp);
}

// Round 6
// 1014.367 us; speedup vs baseline: 1.9800x; 1.0384x over previous
//
#include <hip/hip_runtime.h>
#include <cstdint>

// Problem constants
#define TT 512   // KVLEN
#define CC 512   // C
#define HH 8     // heads
#define NN 64    // head dim
#define BQ 32    // BATCH*QLEN
#define NB 4     // BATCH

__device__ __forceinline__ float sigm(float x){ return 1.f/(1.f+__expf(-x)); }

__device__ __forceinline__ float wsum(float x){
  #pragma unroll
  for (int o=32;o;o>>=1) x += __shfl_xor(x, o, 64);
  return x;
}

// LDS-only barrier: does NOT drain vmcnt, so global prefetch loads stay in
// flight across steps.
#define LDS_BARRIER() asm volatile("s_waitcnt lgkmcnt(0)\n\ts_barrier" ::: "memory")

// ---------------------------------------------------------------------------
// k_prep: per-bq small dots (32 blocks): Qw[bq,32], Qa[bq,32], gh[bq,96],
// and xr row -> workspace.
// ---------------------------------------------------------------------------
__global__ __launch_bounds__(256) void k_prep(
  const float* __restrict__ q, const float* __restrict__ kv,
  const float* __restrict__ x_r, const float* __restrict__ x_w,
  const float* __restrict__ x_a, const float* __restrict__ x_g,
  const float* __restrict__ w1, const float* __restrict__ a1,
  const float* __restrict__ g1,
  float* __restrict__ Qw, float* __restrict__ Qa,
  float* __restrict__ ghw, float* __restrict__ xrw)
{
  int bq = blockIdx.x, b = bq >> 3, tid = threadIdx.x;
  int wave = tid >> 6, lane = tid & 63;
  __shared__ float qxw[CC], qxa[CC], sxg[CC];
  for (int c = tid; c < CC; c += 256){
    float qv = q[bq*CC + c];
    float kl = kv[((size_t)b*TT + (TT-1))*CC + c];
    xrw[bq*CC + c] = kl + (qv - kl)*x_r[c];
    sxg[c] = kl + (qv - kl)*x_g[c];
    qxw[c] = qv*x_w[c];
    qxa[c] = qv*x_a[c];
  }
  __syncthreads();
  for (int dot = wave; dot < 160; dot += 4){
    const float* buf; const float* W; int ld, dd;
    if (dot < 32)      { buf = qxw; W = w1; ld = 32; dd = dot; }
    else if (dot < 64) { buf = qxa; W = a1; ld = 32; dd = dot-32; }
    else               { buf = sxg; W = g1; ld = 96; dd = dot-64; }
    float s = 0.f;
    #pragma unroll
    for (int m = 0; m < 8; m++){
      int c = m*64 + lane;
      s = fmaf(buf[c], W[c*ld + dd], s);
    }
    s = wsum(s);
    if (lane == 0){
      if (dot < 32)      Qw[bq*32 + dd] = s;
      else if (dot < 64) Qa[bq*32 + dd] = s;
      else               ghw[bq*96 + dd] = sigm(s);
    }
  }
}

// ---------------------------------------------------------------------------
// k_rg: rrow[bq,co] = xr[bq,:]@Wr[:,co], grow[bq,co] = gh[bq,:]@g2[:,co]
// ---------------------------------------------------------------------------
__global__ __launch_bounds__(256) void k_rg(
  const float* __restrict__ xrw, const float* __restrict__ ghw,
  const float* __restrict__ Wr, const float* __restrict__ g2,
  float* __restrict__ rrow, float* __restrict__ grow)
{
  int bq = blockIdx.y; int co0 = blockIdx.x*64;
  int tid = threadIdx.x, tx = tid & 63, ty = tid >> 6;
  __shared__ float sxr[CC];
  __shared__ float sgh[96];
  __shared__ float red[4][64];
  sxr[tid]     = xrw[bq*CC + tid];
  sxr[tid+256] = xrw[bq*CC + tid + 256];
  if (tid < 96) sgh[tid] = ghw[bq*96 + tid];
  __syncthreads();
  float p = 0.f;
  for (int i = 0; i < 128; i++){
    int c = ty*128 + i;
    p = fmaf(sxr[c], Wr[(size_t)c*CC + co0 + tx], p);
  }
  red[ty][tx] = p;
  float pg = 0.f;
  for (int d = ty*24; d < ty*24 + 24; d++)
    pg = fmaf(sgh[d], g2[(size_t)d*CC + co0 + tx], pg);
  __syncthreads();
  if (ty == 0)
    rrow[bq*CC + co0 + tx] = (red[0][tx]+red[1][tx])+(red[2][tx]+red[3][tx]);
  __syncthreads();
  red[ty][tx] = pg;
  __syncthreads();
  if (ty == 0)
    grow[bq*CC + co0 + tx] = (red[0][tx]+red[1][tx])+(red[2][tx]+red[3][tx]);
}

// ---------------------------------------------------------------------------
// K1: per-(b,t) (2048 rows)
// ---------------------------------------------------------------------------
__global__ __launch_bounds__(256) void k_perbt(
  const float* __restrict__ kv,
  const float* __restrict__ x_k, const float* __restrict__ x_v,
  const float* __restrict__ x_w, const float* __restrict__ x_a,
  const float* __restrict__ w1, const float* __restrict__ a1,
  const float* __restrict__ v0, const float* __restrict__ v1,
  const float* __restrict__ v2,
  float* __restrict__ xk, float* __restrict__ xv,
  float* __restrict__ Pw, float* __restrict__ Pa,
  float* __restrict__ svv)
{
  int bt = blockIdx.x; int t = bt & (TT-1); int tid = threadIdx.x;
  int wave = tid >> 6, lane = tid & 63;
  const float* cur = kv + (size_t)bt*CC;
  __shared__ float sxv[CC], sxw[CC], sxa[CC], hv[32];
  for (int c = tid; c < CC; c += 256){
    float x  = cur[c];
    float sh = t ? cur[c - CC] : 0.f;
    float d  = sh - x;
    float xkc = x + d*x_k[c];
    float xvc = x + d*x_v[c];
    xk[(size_t)bt*CC + c] = xkc;
    xv[(size_t)bt*CC + c] = xvc;
    sxv[c] = xvc;
    sxw[c] = x*(1.f - x_w[c]);
    sxa[c] = x*(1.f - x_a[c]);
  }
  __syncthreads();
  for (int dot = wave; dot < 96; dot += 4){
    const float* buf = (dot < 32) ? sxw : (dot < 64) ? sxa : sxv;
    const float* W   = (dot < 32) ? w1  : (dot < 64) ? a1  : v1;
    int dd = dot & 31;
    float s = 0.f;
    #pragma unroll
    for (int m = 0; m < 8; m++){
      int c = m*64 + lane;
      s = fmaf(buf[c], W[c*32 + dd], s);
    }
    s = wsum(s);
    if (lane == 0){
      if (dot < 32)      Pw[bt*32 + dd] = s;
      else if (dot < 64) Pa[bt*32 + dd] = s;
      else               hv[dd] = s;
    }
  }
  __syncthreads();
  for (int c = tid; c < CC; c += 256){
    float s = 0.f;
    #pragma unroll
    for (int d = 0; d < 32; d++) s += hv[d]*v2[d*CC + c];
    svv[(size_t)bt*CC + c] = sigm(v0[c] + s);
  }
}

// ---------------------------------------------------------------------------
// Tiled fp32 GEMM: C[2048x512] = A[2048x512] @ W[512x512]. 64x64 tile.
// ---------------------------------------------------------------------------
__global__ __launch_bounds__(256) void gemm_2048_512(
  const float* __restrict__ A, const float* __restrict__ W, float* __restrict__ Co)
{
  __shared__ float As[32][68];
  __shared__ float Bs[32][64];
  int tid = threadIdx.x;
  int tx = tid & 15, ty = tid >> 4;
  int m0 = blockIdx.y*64, n0 = blockIdx.x*64;
  float acc[4][4];
  #pragma unroll
  for (int i=0;i<4;i++)
    #pragma unroll
    for (int j=0;j<4;j++) acc[i][j]=0.f;

  for (int k0 = 0; k0 < 512; k0 += 32){
    #pragma unroll
    for (int i = 0; i < 8; i++){
      int e = tid + i*256;
      int kk = e & 31, m = e >> 5;
      As[kk][m] = A[(size_t)(m0+m)*512 + k0 + kk];
    }
    #pragma unroll
    for (int i = 0; i < 8; i++){
      int e = tid + i*256;
      int n = e & 63, kk = e >> 6;
      Bs[kk][n] = W[(size_t)(k0+kk)*512 + n0 + n];
    }
    __syncthreads();
    #pragma unroll
    for (int kk = 0; kk < 32; kk++){
      float a4[4], b4[4];
      #pragma unroll
      for (int i=0;i<4;i++) a4[i] = As[kk][ty*4+i];
      #pragma unroll
      for (int j=0;j<4;j++) b4[j] = Bs[kk][tx*4+j];
      #pragma unroll
      for (int i=0;i<4;i++)
        #pragma unroll
        for (int j=0;j<4;j++) acc[i][j] += a4[i]*b4[j];
    }
    __syncthreads();
  }
  #pragma unroll
  for (int i=0;i<4;i++)
    #pragma unroll
    for (int j=0;j<4;j++)
      Co[(size_t)(m0+ty*4+i)*512 + n0 + tx*4 + j] = acc[i][j];
}

// ---------------------------------------------------------------------------
// K1b: kk = normalize_per_head(k * k_k)
// ---------------------------------------------------------------------------
__global__ __launch_bounds__(512) void k_kk(
  const float* __restrict__ kg, const float* __restrict__ k_k,
  float* __restrict__ kkg)
{
  int bt = blockIdx.x, tid = threadIdx.x;
  float v = kg[(size_t)bt*CC + tid]*k_k[tid];
  float ss = wsum(v*v);
  float nrm = fmaxf(sqrtf(ss), 1e-12f);
  kkg[(size_t)bt*CC + tid] = v/nrm;
}

// ---------------------------------------------------------------------------
// K2: per (bq,t,c): decay w, k_final, b_vec = kk*a.  4 rows per block;
// th/al staged in LDS (tanh fused); w2/a2 columns in registers across rows.
// ---------------------------------------------------------------------------
__global__ __launch_bounds__(256) void k_wkb(
  const float* __restrict__ Pw, const float* __restrict__ Pa,
  const float* __restrict__ Qw, const float* __restrict__ Qa,
  const float* __restrict__ w2, const float* __restrict__ a2,
  const float* __restrict__ w0, const float* __restrict__ a0,
  const float* __restrict__ k_a, const float* __restrict__ kg,
  const float* __restrict__ kkg,
  float* __restrict__ wS, float* __restrict__ kS, float* __restrict__ bS)
{
  int bqt0 = blockIdx.x*4;           // 4 consecutive t within one bq
  int bq = bqt0 >> 9, t0 = bqt0 & (TT-1), b = bq >> 3;
  int tid = threadIdx.x;
  __shared__ float sth[4][32], sal[4][32];
  {
    int g = (tid >> 5) & 3, d = tid & 31;
    int pidx = ((b << 9) | (t0 + g))*32 + d;
    if (tid < 128) sth[g][d] = tanhf(Pw[pidx] + Qw[bq*32 + d]);
    else           sal[g][d] = Pa[pidx] + Qa[bq*32 + d];
  }
  __syncthreads();
  #pragma unroll
  for (int cc = 0; cc < 2; cc++){
    int c = tid + cc*256;
    float wreg[32], areg[32];
    #pragma unroll
    for (int d = 0; d < 32; d++){ wreg[d] = w2[d*CC + c]; areg[d] = a2[d*CC + c]; }
    float w0c = w0[c], a0c = a0[c], kac = k_a[c];
    #pragma unroll
    for (int g = 0; g < 4; g++){
      float wa = 0.f, aa = 0.f;
      #pragma unroll
      for (int d = 0; d < 32; d++){
        wa = fmaf(sth[g][d], wreg[d], wa);
        aa = fmaf(sal[g][d], areg[d], aa);
      }
      float a_sig = sigm(a0c + aa);
      float wdec  = __expf(-0.60653066f * sigm(w0c + wa));
      size_t bt = (size_t)((b << 9) | (t0 + g));
      size_t o  = (size_t)(bqt0 + g)*CC + c;
      float kvv = kg[bt*CC + c];
      float kkv = kkg[bt*CC + c];
      wS[o] = wdec;
      kS[o] = kvv*(1.f + (a_sig - 1.f)*kac);
      bS[o] = kkv*a_sig;
    }
  }
}

// ---------------------------------------------------------------------------
// K3: scan, 4 waves per (bq,h). Wave w owns state columns [16w,16w+16);
// lane = row i.  Staging role: comp=lane&3 (0=w,1=k,2=b,3=kk_next),
// col=wave*16+(lane>>2) -> LDS write index 64*wave+lane (linear, conflict-free).
// Inner loop: ALL 16 coefficient quads loaded into a register array cq[16]
// up front (forces back-to-back ds_read_b128 issue, one lgkmcnt wait), then
// the 48-FMA update stream with a 4-way-split pn accumulator.
// [R5 bug-class fixed: VGPR=32 starved the LDS reads into serialized batches]
// ---------------------------------------------------------------------------
__global__ __launch_bounds__(256, 1) void k_scan(
  const float* __restrict__ wv, const float* __restrict__ kf,
  const float* __restrict__ bv, const float* __restrict__ kkg,
  const float* __restrict__ vpre, const float* __restrict__ svv,
  const float* __restrict__ vfirst,
  const float* __restrict__ rrow, const float* __restrict__ grow,
  const float* __restrict__ r_k, const float* __restrict__ ln_w,
  const float* __restrict__ ln_b, float* __restrict__ xo)
{
  __shared__ __align__(16) float stage[2][256];  // dword 4*col+comp
  __shared__ float psa[2][256];                  // [wave*64 + row]
  __shared__ float pout[256];
  __shared__ float vbuf[2][64];
  int blk = blockIdx.x; int bq = blk >> 3, h = blk & 7, b = bq >> 3;
  int tid = threadIdx.x; int wave = tid >> 6; int lane = tid & 63;
  size_t cb_bq = (size_t)bq*TT*CC + h*NN;
  size_t cb_b  = (size_t)b*TT*CC + h*NN;

  // staging role
  int comp = lane & 3, col = wave*16 + (lane >> 2);
  const float* basep; size_t lbase; int tmaxl;
  if      (comp == 0){ basep = wv;  lbase = cb_bq + col;     tmaxl = TT-1; }
  else if (comp == 1){ basep = kf;  lbase = cb_bq + col;     tmaxl = TT-1; }
  else if (comp == 2){ basep = bv;  lbase = cb_bq + col;     tmaxl = TT-1; }
  else               { basep = kkg; lbase = cb_b + CC + col; tmaxl = TT-2; }

  float st[16];
  #pragma unroll
  for (int jj = 0; jj < 16; jj++) st[jj] = 0.f;
  psa[0][tid] = 0.f;

  // stage t=0 directly; register pipeline Pold=data(1), Pnew=data(2)
  stage[0][tid] = basep[lbase];
  float Pold = basep[lbase + CC];
  float Pnew = basep[lbase + 2*CC];

  // v pipeline (wave 0): vbuf[t&1][i] = v_t[i]
  float vpc=0.f, svc=0.f, vfc=0.f, vpn=0.f, svn=0.f, vfn=0.f;
  if (wave == 0){
    float vp0 = vpre[cb_b + lane], sv0 = svv[cb_b + lane], vf0 = vfirst[cb_bq + lane];
    vbuf[0][lane] = vp0 + (vf0 - vp0)*sv0;
    vpc = vpre[cb_b + CC + lane]; svc = svv[cb_b + CC + lane]; vfc = vfirst[cb_bq + CC + lane];
    vpn = vpre[cb_b + 2*CC + lane]; svn = svv[cb_b + 2*CC + lane]; vfn = vfirst[cb_bq + 2*CC + lane];
  }
  LDS_BARRIER();

  float v_i = 0.f;
  for (int t = 0; t < TT; t++){
    // pull this step's 16 coefficient quads into registers FIRST
    // (back-to-back ds_read_b128; single wait; no serialized batches)
    float4 cq[16];
    {
      const float4* cv = (const float4*)stage[t&1];
      #pragma unroll
      for (int jj = 0; jj < 16; jj++) cq[jj] = cv[wave*16 + jj];
    }
    // sa partials + v broadcast (LDS reads, same wait window)
    float p0 = psa[t&1][lane],       p1 = psa[t&1][64 + lane];
    float p2 = psa[t&1][128 + lane], p3 = psa[t&1][192 + lane];
    v_i = vbuf[t&1][lane];

    // publish data(t+1) into the other stage buffer; advance prefetch (t+3)
    stage[(t+1)&1][tid] = Pold;
    Pold = Pnew;
    {
      int te = t+3; te = (te > tmaxl) ? tmaxl : te;
      Pnew = basep[lbase + (size_t)te*CC];
    }
    if (wave == 0){
      vbuf[(t+1)&1][lane] = vpc + (vfc - vpc)*svc;   // v_{t+1}
      vpc = vpn; svc = svn; vfc = vfn;
      int tv = (t+3 < TT) ? t+3 : TT-1;
      vpn = vpre[cb_b + (size_t)tv*CC + lane];
      svn = svv [cb_b + (size_t)tv*CC + lane];
      vfn = vfirst[cb_bq + (size_t)tv*CC + lane];
    }

    float sa = -((p0 + p1) + (p2 + p3));
    float pn0=0.f, pn1=0.f, pn2=0.f, pn3=0.f;
    #pragma unroll
    for (int jj = 0; jj < 16; jj += 4){
      st[jj  ] = fmaf(st[jj  ], cq[jj  ].x, fmaf(sa, cq[jj  ].z, v_i*cq[jj  ].y));
      st[jj+1] = fmaf(st[jj+1], cq[jj+1].x, fmaf(sa, cq[jj+1].z, v_i*cq[jj+1].y));
      st[jj+2] = fmaf(st[jj+2], cq[jj+2].x, fmaf(sa, cq[jj+2].z, v_i*cq[jj+2].y));
      st[jj+3] = fmaf(st[jj+3], cq[jj+3].x, fmaf(sa, cq[jj+3].z, v_i*cq[jj+3].y));
      pn0 = fmaf(st[jj  ], cq[jj  ].w, pn0);
      pn1 = fmaf(st[jj+1], cq[jj+1].w, pn1);
      pn2 = fmaf(st[jj+2], cq[jj+2].w, pn2);
      pn3 = fmaf(st[jj+3], cq[jj+3].w, pn3);
    }
    psa[(t+1)&1][tid] = (pn0+pn1)+(pn2+pn3);
    LDS_BARRIER();
  }

  // epilogue: out_i = sum_j S[i,j] r[j]
  {
    const float* rp = rrow + (size_t)bq*CC + h*NN;
    float po = 0.f;
    #pragma unroll
    for (int jj = 0; jj < 16; jj++) po = fmaf(st[jj], rp[wave*16 + jj], po);
    pout[tid] = po;
  }
  __syncthreads();
  if (wave == 0){
    float out = (pout[lane] + pout[64+lane]) + (pout[128+lane] + pout[192+lane]);
    float mean = wsum(out) * (1.f/NN);
    float dv = out - mean;
    float var = wsum(dv*dv) * (1.f/NN);
    float yn = dv * rsqrtf(var + 6.4e-4f);   // GN_EPS = 1e-5*64
    int c = h*NN + lane;
    float y2 = yn * ln_w[c] + ln_b[c];
    float kl = kf[cb_bq + (size_t)(TT-1)*CC + lane];
    float rl = rrow[(size_t)bq*CC + h*NN + lane];
    float rk = wsum(rl*kl*r_k[c]);
    float res = (y2 + rk*v_i) * grow[(size_t)bq*CC + c];
    xo[bq*CC + c] = res;
  }
}

// ---------------------------------------------------------------------------
// K4: out[bq,co] = xo[bq,:] @ Wo[:,co]
// ---------------------------------------------------------------------------
__global__ __launch_bounds__(256) void k_out(
  const float* __restrict__ xo, const float* __restrict__ Wo,
  float* __restrict__ outp)
{
  int bq = blockIdx.y; int co0 = blockIdx.x*64;
  int tid = threadIdx.x, tx = tid & 63, ty = tid >> 6;
  __shared__ float row[CC];
  __shared__ float red[4][64];
  row[tid]     = xo[bq*CC + tid];
  row[tid+256] = xo[bq*CC + tid + 256];
  __syncthreads();
  float p = 0.f;
  for (int i = 0; i < 128; i++){
    int c = ty*128 + i;
    p = fmaf(row[c], Wo[(size_t)c*CC + co0 + tx], p);
  }
  red[ty][tx] = p;
  __syncthreads();
  if (ty == 0)
    outp[bq*CC + co0 + tx] = (red[0][tx]+red[1][tx])+(red[2][tx]+red[3][tx]);
}

// ---------------------------------------------------------------------------
extern "C" void kernel_launch(void* const* d_in, const int* in_sizes, int n_in,
                              void* d_out, int out_size, void* d_ws, size_t ws_size,
                              hipStream_t stream)
{
  const float* q   = (const float*)d_in[0];
  const float* kv  = (const float*)d_in[1];
  const float* vf  = (const float*)d_in[2];
  const float* x_r = (const float*)d_in[3];
  const float* x_w = (const float*)d_in[4];
  const float* x_k = (const float*)d_in[5];
  const float* x_v = (const float*)d_in[6];
  const float* x_a = (const float*)d_in[7];
  const float* x_g = (const float*)d_in[8];
  const float* w0  = (const float*)d_in[9];
  const float* w1  = (const float*)d_in[10];
  const float* w2  = (const float*)d_in[11];
  const float* a0  = (const float*)d_in[12];
  const float* a1  = (const float*)d_in[13];
  const float* a2  = (const float*)d_in[14];
  const float* v0  = (const float*)d_in[15];
  const float* v1  = (const float*)d_in[16];
  const float* v2  = (const float*)d_in[17];
  const float* g1  = (const float*)d_in[18];
  const float* g2  = (const float*)d_in[19];
  const float* k_k = (const float*)d_in[20];
  const float* k_a = (const float*)d_in[21];
  const float* r_k = (const float*)d_in[22];
  const float* Wr  = (const float*)d_in[23];
  const float* Wk  = (const float*)d_in[24];
  const float* Wv  = (const float*)d_in[25];
  const float* Wo  = (const float*)d_in[26];
  const float* lnw = (const float*)d_in[27];
  const float* lnb = (const float*)d_in[28];
  float* outp = (float*)d_out;
  float* ws = (float*)d_ws;

  // workspace layout (floats)
  float* xk = ws + 0;         // 4*512*512
  float* xv = ws + 1048576;
  float* kg = ws + 2097152;   // k
  float* vp = ws + 3145728;   // v_pre
  float* sv = ws + 4194304;   // sigmoid lerp factor
  float* kk = ws + 5242880;   // normalized kk
  float* Pw = ws + 6291456;   // 4*512*32
  float* Pa = ws + 6356992;
  float* Qw = ws + 6422528;   // 32*32
  float* Qa = ws + 6423552;
  float* rr = ws + 7473152;   // 32*512
  float* gr = ws + 7489536;
  float* xo = ws + 7505920;
  float* wS = ws + 7522304;   // 32*512*512 decay
  float* kS = ws + 15910912;  // k_final
  float* bS = ws + 24299520;  // kk*a
  float* xrw = ws + 32688128; // 32*512
  float* ghw = ws + 32704512; // 32*96

  // v_first passthrough (tuple output #2)
  hipMemcpyAsync(outp + BQ*CC, vf,
                 (size_t)BQ*TT*CC*sizeof(float), hipMemcpyDeviceToDevice, stream);

  k_prep<<<32, 256, 0, stream>>>(q, kv, x_r, x_w, x_a, x_g, w1, a1, g1,
                                 Qw, Qa, ghw, xrw);
  k_rg<<<dim3(8, 32), 256, 0, stream>>>(xrw, ghw, Wr, g2, rr, gr);
  k_perbt<<<NB*TT, 256, 0, stream>>>(kv, x_k, x_v, x_w, x_a, w1, a1, v0, v1, v2,
                                     xk, xv, Pw, Pa, sv);
  gemm_2048_512<<<dim3(8, 32), 256, 0, stream>>>(xk, Wk, kg);
  gemm_2048_512<<<dim3(8, 32), 256, 0, stream>>>(xv, Wv, vp);
  k_kk<<<NB*TT, 512, 0, stream>>>(kg, k_k, kk);
  k_wkb<<<BQ*TT/4, 256, 0, stream>>>(Pw, Pa, Qw, Qa, w2, a2, w0, a0, k_a,
                                     kg, kk, wS, kS, bS);
  k_scan<<<BQ*HH, 256, 0, stream>>>(wS, kS, bS, kk, vp, sv, vf, rr, gr, r_k,
                                    lnw, lnb, xo);
  k_out<<<dim3(8, 32), 256, 0, stream>>>(xo, Wo, outp);
}

// Round 7
// 687.934 us; speedup vs baseline: 2.9196x; 1.4745x over previous
//
#include <hip/hip_runtime.h>
#include <cstdint>

// Problem constants
#define TT 512   // KVLEN
#define CC 512   // C
#define HH 8     // heads
#define NN 64    // head dim
#define BQ 32    // BATCH*QLEN
#define NB 4     // BATCH

__device__ __forceinline__ float sigm(float x){ return 1.f/(1.f+__expf(-x)); }

__device__ __forceinline__ float wsum(float x){
  #pragma unroll
  for (int o=32;o;o>>=1) x += __shfl_xor(x, o, 64);
  return x;
}

// LDS-only barrier: does NOT drain vmcnt, so global prefetch loads stay in
// flight across steps.
#define LDS_BARRIER() asm volatile("s_waitcnt lgkmcnt(0)\n\ts_barrier" ::: "memory")

// ---------------------------------------------------------------------------
// k_prep: per-bq small dots (32 blocks): Qw[bq,32], Qa[bq,32], gh[bq,96],
// and xr row -> workspace.
// ---------------------------------------------------------------------------
__global__ __launch_bounds__(256) void k_prep(
  const float* __restrict__ q, const float* __restrict__ kv,
  const float* __restrict__ x_r, const float* __restrict__ x_w,
  const float* __restrict__ x_a, const float* __restrict__ x_g,
  const float* __restrict__ w1, const float* __restrict__ a1,
  const float* __restrict__ g1,
  float* __restrict__ Qw, float* __restrict__ Qa,
  float* __restrict__ ghw, float* __restrict__ xrw)
{
  int bq = blockIdx.x, b = bq >> 3, tid = threadIdx.x;
  int wave = tid >> 6, lane = tid & 63;
  __shared__ float qxw[CC], qxa[CC], sxg[CC];
  for (int c = tid; c < CC; c += 256){
    float qv = q[bq*CC + c];
    float kl = kv[((size_t)b*TT + (TT-1))*CC + c];
    xrw[bq*CC + c] = kl + (qv - kl)*x_r[c];
    sxg[c] = kl + (qv - kl)*x_g[c];
    qxw[c] = qv*x_w[c];
    qxa[c] = qv*x_a[c];
  }
  __syncthreads();
  for (int dot = wave; dot < 160; dot += 4){
    const float* buf; const float* W; int ld, dd;
    if (dot < 32)      { buf = qxw; W = w1; ld = 32; dd = dot; }
    else if (dot < 64) { buf = qxa; W = a1; ld = 32; dd = dot-32; }
    else               { buf = sxg; W = g1; ld = 96; dd = dot-64; }
    float s = 0.f;
    #pragma unroll
    for (int m = 0; m < 8; m++){
      int c = m*64 + lane;
      s = fmaf(buf[c], W[c*ld + dd], s);
    }
    s = wsum(s);
    if (lane == 0){
      if (dot < 32)      Qw[bq*32 + dd] = s;
      else if (dot < 64) Qa[bq*32 + dd] = s;
      else               ghw[bq*96 + dd] = sigm(s);
    }
  }
}

// ---------------------------------------------------------------------------
// k_rg: rrow[bq,co] = xr[bq,:]@Wr[:,co], grow[bq,co] = gh[bq,:]@g2[:,co]
// ---------------------------------------------------------------------------
__global__ __launch_bounds__(256) void k_rg(
  const float* __restrict__ xrw, const float* __restrict__ ghw,
  const float* __restrict__ Wr, const float* __restrict__ g2,
  float* __restrict__ rrow, float* __restrict__ grow)
{
  int bq = blockIdx.y; int co0 = blockIdx.x*64;
  int tid = threadIdx.x, tx = tid & 63, ty = tid >> 6;
  __shared__ float sxr[CC];
  __shared__ float sgh[96];
  __shared__ float red[4][64];
  sxr[tid]     = xrw[bq*CC + tid];
  sxr[tid+256] = xrw[bq*CC + tid + 256];
  if (tid < 96) sgh[tid] = ghw[bq*96 + tid];
  __syncthreads();
  float p = 0.f;
  for (int i = 0; i < 128; i++){
    int c = ty*128 + i;
    p = fmaf(sxr[c], Wr[(size_t)c*CC + co0 + tx], p);
  }
  red[ty][tx] = p;
  float pg = 0.f;
  for (int d = ty*24; d < ty*24 + 24; d++)
    pg = fmaf(sgh[d], g2[(size_t)d*CC + co0 + tx], pg);
  __syncthreads();
  if (ty == 0)
    rrow[bq*CC + co0 + tx] = (red[0][tx]+red[1][tx])+(red[2][tx]+red[3][tx]);
  __syncthreads();
  red[ty][tx] = pg;
  __syncthreads();
  if (ty == 0)
    grow[bq*CC + co0 + tx] = (red[0][tx]+red[1][tx])+(red[2][tx]+red[3][tx]);
}

// ---------------------------------------------------------------------------
// k_shift: elementwise token-shift mix (replaces k_perbt's staging):
//   xk = x + (shift - x)*x_k ; xv = x + (shift - x)*x_v.  float4, coalesced.
// ---------------------------------------------------------------------------
__global__ __launch_bounds__(256) void k_shift(
  const float* __restrict__ kv, const float* __restrict__ x_k,
  const float* __restrict__ x_v,
  float* __restrict__ xk, float* __restrict__ xv)
{
  int g = blockIdx.x*256 + threadIdx.x;      // float4 index, [0, 262144)
  int bt = g >> 7, t = bt & (TT-1), c4 = g & 127;
  const float4* kv4 = (const float4*)kv;
  float4 cur = kv4[g];
  float4 sh  = t ? kv4[g-128] : make_float4(0.f,0.f,0.f,0.f);
  float4 kc  = ((const float4*)x_k)[c4];
  float4 vc  = ((const float4*)x_v)[c4];
  float4 ok, ov;
  ok.x = cur.x + (sh.x-cur.x)*kc.x; ov.x = cur.x + (sh.x-cur.x)*vc.x;
  ok.y = cur.y + (sh.y-cur.y)*kc.y; ov.y = cur.y + (sh.y-cur.y)*vc.y;
  ok.z = cur.z + (sh.z-cur.z)*kc.z; ov.z = cur.z + (sh.z-cur.z)*vc.z;
  ok.w = cur.w + (sh.w-cur.w)*kc.w; ov.w = cur.w + (sh.w-cur.w)*vc.w;
  ((float4*)xk)[g] = ok;
  ((float4*)xv)[g] = ov;
}

// ---------------------------------------------------------------------------
// k_pgemm: the three [2048x512]@[512x32] products as a proper tiled GEMM
// (replaces the uncoalesced wave-dots that blew up L2: 6.4 GB -> ~6 MB):
//   mat 0: A[r,c]=kv[r,c]*(1-x_w[c]), B=w1 -> Pw
//   mat 1: A[r,c]=kv[r,c]*(1-x_a[c]), B=a1 -> Pa
//   mat 2: A=xv,                      B=v1 -> HV
// Grid (32 row-tiles, 3 mats), M=64 N=32 Kc=32, 8 outputs/thread.
// ---------------------------------------------------------------------------
__global__ __launch_bounds__(256) void k_pgemm(
  const float* __restrict__ kv, const float* __restrict__ xv,
  const float* __restrict__ x_w, const float* __restrict__ x_a,
  const float* __restrict__ w1, const float* __restrict__ a1,
  const float* __restrict__ v1,
  float* __restrict__ Pw, float* __restrict__ Pa, float* __restrict__ HV)
{
  int mat = blockIdx.y;
  int r0 = blockIdx.x * 64;
  const float* A = (mat == 2) ? xv : kv;
  const float* B = (mat == 0) ? w1 : (mat == 1) ? a1 : v1;
  float* O       = (mat == 0) ? Pw : (mat == 1) ? Pa : HV;
  int tid = threadIdx.x;
  __shared__ float As[32][65];   // [k][r], stride 65: conflict-free both ways
  __shared__ float Bs[32][32];   // [k][n]
  __shared__ float scl[CC];
  for (int c = tid; c < CC; c += 256)
    scl[c] = (mat == 0) ? (1.f - x_w[c]) : (mat == 1) ? (1.f - x_a[c]) : 1.f;
  __syncthreads();
  int tx = tid & 31, ty = tid >> 5;
  float acc[8];
  #pragma unroll
  for (int i = 0; i < 8; i++) acc[i] = 0.f;
  for (int k0 = 0; k0 < 512; k0 += 32){
    #pragma unroll
    for (int p = 0; p < 8; p++){       // stage A: 64 rows x 32 k
      int e = tid + p*256;
      int kk2 = e & 31, r = e >> 5;
      As[kk2][r] = A[(size_t)(r0+r)*512 + k0 + kk2] * scl[k0 + kk2];
    }
    #pragma unroll
    for (int p = 0; p < 4; p++){       // stage B: 32 k x 32 n
      int e = tid + p*256;
      int n = e & 31, kk2 = e >> 5;
      Bs[kk2][n] = B[(size_t)(k0+kk2)*32 + n];
    }
    __syncthreads();
    #pragma unroll
    for (int kk2 = 0; kk2 < 32; kk2++){
      float bb = Bs[kk2][tx];
      #pragma unroll
      for (int i = 0; i < 8; i++)
        acc[i] = fmaf(As[kk2][ty*8 + i], bb, acc[i]);
    }
    __syncthreads();
  }
  #pragma unroll
  for (int i = 0; i < 8; i++)
    O[(size_t)(r0 + ty*8 + i)*32 + tx] = acc[i];
}

// ---------------------------------------------------------------------------
// k_sv: sv[bt,c] = sigm(v0[c] + HV[bt,:]@v2[:,c])   (2048 blocks, coalesced v2)
// ---------------------------------------------------------------------------
__global__ __launch_bounds__(256) void k_sv(
  const float* __restrict__ HV, const float* __restrict__ v2,
  const float* __restrict__ v0, float* __restrict__ svv)
{
  int bt = blockIdx.x, tid = threadIdx.x;
  __shared__ float hv[32];
  if (tid < 32) hv[tid] = HV[bt*32 + tid];
  __syncthreads();
  for (int c = tid; c < CC; c += 256){
    float s = 0.f;
    #pragma unroll
    for (int d = 0; d < 32; d++) s = fmaf(hv[d], v2[d*CC + c], s);
    svv[(size_t)bt*CC + c] = sigm(v0[c] + s);
  }
}

// ---------------------------------------------------------------------------
// Tiled fp32 GEMM: C[2048x512] = A[2048x512] @ W[512x512]. 64x64 tile.
// ---------------------------------------------------------------------------
__global__ __launch_bounds__(256) void gemm_2048_512(
  const float* __restrict__ A, const float* __restrict__ W, float* __restrict__ Co)
{
  __shared__ float As[32][68];
  __shared__ float Bs[32][64];
  int tid = threadIdx.x;
  int tx = tid & 15, ty = tid >> 4;
  int m0 = blockIdx.y*64, n0 = blockIdx.x*64;
  float acc[4][4];
  #pragma unroll
  for (int i=0;i<4;i++)
    #pragma unroll
    for (int j=0;j<4;j++) acc[i][j]=0.f;

  for (int k0 = 0; k0 < 512; k0 += 32){
    #pragma unroll
    for (int i = 0; i < 8; i++){
      int e = tid + i*256;
      int kk = e & 31, m = e >> 5;
      As[kk][m] = A[(size_t)(m0+m)*512 + k0 + kk];
    }
    #pragma unroll
    for (int i = 0; i < 8; i++){
      int e = tid + i*256;
      int n = e & 63, kk = e >> 6;
      Bs[kk][n] = W[(size_t)(k0+kk)*512 + n0 + n];
    }
    __syncthreads();
    #pragma unroll
    for (int kk = 0; kk < 32; kk++){
      float a4[4], b4[4];
      #pragma unroll
      for (int i=0;i<4;i++) a4[i] = As[kk][ty*4+i];
      #pragma unroll
      for (int j=0;j<4;j++) b4[j] = Bs[kk][tx*4+j];
      #pragma unroll
      for (int i=0;i<4;i++)
        #pragma unroll
        for (int j=0;j<4;j++) acc[i][j] += a4[i]*b4[j];
    }
    __syncthreads();
  }
  #pragma unroll
  for (int i=0;i<4;i++)
    #pragma unroll
    for (int j=0;j<4;j++)
      Co[(size_t)(m0+ty*4+i)*512 + n0 + tx*4 + j] = acc[i][j];
}

// ---------------------------------------------------------------------------
// K1b: kk = normalize_per_head(k * k_k)
// ---------------------------------------------------------------------------
__global__ __launch_bounds__(512) void k_kk(
  const float* __restrict__ kg, const float* __restrict__ k_k,
  float* __restrict__ kkg)
{
  int bt = blockIdx.x, tid = threadIdx.x;
  float v = kg[(size_t)bt*CC + tid]*k_k[tid];
  float ss = wsum(v*v);
  float nrm = fmaxf(sqrtf(ss), 1e-12f);
  kkg[(size_t)bt*CC + tid] = v/nrm;
}

// ---------------------------------------------------------------------------
// K2: per (bq,t,c): decay w, k_final, b_vec = kk*a.  4 rows per block.
// ---------------------------------------------------------------------------
__global__ __launch_bounds__(256) void k_wkb(
  const float* __restrict__ Pw, const float* __restrict__ Pa,
  const float* __restrict__ Qw, const float* __restrict__ Qa,
  const float* __restrict__ w2, const float* __restrict__ a2,
  const float* __restrict__ w0, const float* __restrict__ a0,
  const float* __restrict__ k_a, const float* __restrict__ kg,
  const float* __restrict__ kkg,
  float* __restrict__ wS, float* __restrict__ kS, float* __restrict__ bS)
{
  int bqt0 = blockIdx.x*4;           // 4 consecutive t within one bq
  int bq = bqt0 >> 9, t0 = bqt0 & (TT-1), b = bq >> 3;
  int tid = threadIdx.x;
  __shared__ float sth[4][32], sal[4][32];
  {
    int g = (tid >> 5) & 3, d = tid & 31;
    int pidx = ((b << 9) | (t0 + g))*32 + d;
    if (tid < 128) sth[g][d] = tanhf(Pw[pidx] + Qw[bq*32 + d]);
    else           sal[g][d] = Pa[pidx] + Qa[bq*32 + d];
  }
  __syncthreads();
  #pragma unroll
  for (int cc = 0; cc < 2; cc++){
    int c = tid + cc*256;
    float wreg[32], areg[32];
    #pragma unroll
    for (int d = 0; d < 32; d++){ wreg[d] = w2[d*CC + c]; areg[d] = a2[d*CC + c]; }
    float w0c = w0[c], a0c = a0[c], kac = k_a[c];
    #pragma unroll
    for (int g = 0; g < 4; g++){
      float wa = 0.f, aa = 0.f;
      #pragma unroll
      for (int d = 0; d < 32; d++){
        wa = fmaf(sth[g][d], wreg[d], wa);
        aa = fmaf(sal[g][d], areg[d], aa);
      }
      float a_sig = sigm(a0c + aa);
      float wdec  = __expf(-0.60653066f * sigm(w0c + wa));
      size_t bt = (size_t)((b << 9) | (t0 + g));
      size_t o  = (size_t)(bqt0 + g)*CC + c;
      float kvv = kg[bt*CC + c];
      float kkv = kkg[bt*CC + c];
      wS[o] = wdec;
      kS[o] = kvv*(1.f + (a_sig - 1.f)*kac);
      bS[o] = kkv*a_sig;
    }
  }
}

// ---------------------------------------------------------------------------
// K3: scan, 4 waves per (bq,h).  (unchanged from R5)
// ---------------------------------------------------------------------------
__global__ __launch_bounds__(256, 1) void k_scan(
  const float* __restrict__ wv, const float* __restrict__ kf,
  const float* __restrict__ bv, const float* __restrict__ kkg,
  const float* __restrict__ vpre, const float* __restrict__ svv,
  const float* __restrict__ vfirst,
  const float* __restrict__ rrow, const float* __restrict__ grow,
  const float* __restrict__ r_k, const float* __restrict__ ln_w,
  const float* __restrict__ ln_b, float* __restrict__ xo)
{
  __shared__ __align__(16) float stage[2][256];  // dword 4*col+comp
  __shared__ float psa[2][256];                  // [wave*64 + row]
  __shared__ float pout[256];
  __shared__ float vbuf[2][64];
  int blk = blockIdx.x; int bq = blk >> 3, h = blk & 7, b = bq >> 3;
  int tid = threadIdx.x; int wave = tid >> 6; int lane = tid & 63;
  size_t cb_bq = (size_t)bq*TT*CC + h*NN;
  size_t cb_b  = (size_t)b*TT*CC + h*NN;

  int comp = lane & 3, col = wave*16 + (lane >> 2);
  const float* basep; size_t lbase; int tmaxl;
  if      (comp == 0){ basep = wv;  lbase = cb_bq + col;     tmaxl = TT-1; }
  else if (comp == 1){ basep = kf;  lbase = cb_bq + col;     tmaxl = TT-1; }
  else if (comp == 2){ basep = bv;  lbase = cb_bq + col;     tmaxl = TT-1; }
  else               { basep = kkg; lbase = cb_b + CC + col; tmaxl = TT-2; }

  float st[16];
  #pragma unroll
  for (int jj = 0; jj < 16; jj++) st[jj] = 0.f;
  psa[0][tid] = 0.f;

  stage[0][tid] = basep[lbase];
  float Pold = basep[lbase + CC];
  float Pnew = basep[lbase + 2*CC];

  float vpc=0.f, svc=0.f, vfc=0.f, vpn=0.f, svn=0.f, vfn=0.f;
  if (wave == 0){
    float vp0 = vpre[cb_b + lane], sv0 = svv[cb_b + lane], vf0 = vfirst[cb_bq + lane];
    vbuf[0][lane] = vp0 + (vf0 - vp0)*sv0;
    vpc = vpre[cb_b + CC + lane]; svc = svv[cb_b + CC + lane]; vfc = vfirst[cb_bq + CC + lane];
    vpn = vpre[cb_b + 2*CC + lane]; svn = svv[cb_b + 2*CC + lane]; vfn = vfirst[cb_bq + 2*CC + lane];
  }
  LDS_BARRIER();

  float v_i = 0.f;
  for (int t = 0; t < TT; t++){
    float4 cq[16];
    {
      const float4* cv = (const float4*)stage[t&1];
      #pragma unroll
      for (int jj = 0; jj < 16; jj++) cq[jj] = cv[wave*16 + jj];
    }
    float p0 = psa[t&1][lane],       p1 = psa[t&1][64 + lane];
    float p2 = psa[t&1][128 + lane], p3 = psa[t&1][192 + lane];
    v_i = vbuf[t&1][lane];

    stage[(t+1)&1][tid] = Pold;
    Pold = Pnew;
    {
      int te = t+3; te = (te > tmaxl) ? tmaxl : te;
      Pnew = basep[lbase + (size_t)te*CC];
    }
    if (wave == 0){
      vbuf[(t+1)&1][lane] = vpc + (vfc - vpc)*svc;   // v_{t+1}
      vpc = vpn; svc = svn; vfc = vfn;
      int tv = (t+3 < TT) ? t+3 : TT-1;
      vpn = vpre[cb_b + (size_t)tv*CC + lane];
      svn = svv [cb_b + (size_t)tv*CC + lane];
      vfn = vfirst[cb_bq + (size_t)tv*CC + lane];
    }

    float sa = -((p0 + p1) + (p2 + p3));
    float pn0=0.f, pn1=0.f, pn2=0.f, pn3=0.f;
    #pragma unroll
    for (int jj = 0; jj < 16; jj += 4){
      st[jj  ] = fmaf(st[jj  ], cq[jj  ].x, fmaf(sa, cq[jj  ].z, v_i*cq[jj  ].y));
      st[jj+1] = fmaf(st[jj+1], cq[jj+1].x, fmaf(sa, cq[jj+1].z, v_i*cq[jj+1].y));
      st[jj+2] = fmaf(st[jj+2], cq[jj+2].x, fmaf(sa, cq[jj+2].z, v_i*cq[jj+2].y));
      st[jj+3] = fmaf(st[jj+3], cq[jj+3].x, fmaf(sa, cq[jj+3].z, v_i*cq[jj+3].y));
      pn0 = fmaf(st[jj  ], cq[jj  ].w, pn0);
      pn1 = fmaf(st[jj+1], cq[jj+1].w, pn1);
      pn2 = fmaf(st[jj+2], cq[jj+2].w, pn2);
      pn3 = fmaf(st[jj+3], cq[jj+3].w, pn3);
    }
    psa[(t+1)&1][tid] = (pn0+pn1)+(pn2+pn3);
    LDS_BARRIER();
  }

  {
    const float* rp = rrow + (size_t)bq*CC + h*NN;
    float po = 0.f;
    #pragma unroll
    for (int jj = 0; jj < 16; jj++) po = fmaf(st[jj], rp[wave*16 + jj], po);
    pout[tid] = po;
  }
  __syncthreads();
  if (wave == 0){
    float out = (pout[lane] + pout[64+lane]) + (pout[128+lane] + pout[192+lane]);
    float mean = wsum(out) * (1.f/NN);
    float dv = out - mean;
    float var = wsum(dv*dv) * (1.f/NN);
    float yn = dv * rsqrtf(var + 6.4e-4f);   // GN_EPS = 1e-5*64
    int c = h*NN + lane;
    float y2 = yn * ln_w[c] + ln_b[c];
    float kl = kf[cb_bq + (size_t)(TT-1)*CC + lane];
    float rl = rrow[(size_t)bq*CC + h*NN + lane];
    float rk = wsum(rl*kl*r_k[c]);
    float res = (y2 + rk*v_i) * grow[(size_t)bq*CC + c];
    xo[bq*CC + c] = res;
  }
}

// ---------------------------------------------------------------------------
// K4: out[bq,co] = xo[bq,:] @ Wo[:,co]
// ---------------------------------------------------------------------------
__global__ __launch_bounds__(256) void k_out(
  const float* __restrict__ xo, const float* __restrict__ Wo,
  float* __restrict__ outp)
{
  int bq = blockIdx.y; int co0 = blockIdx.x*64;
  int tid = threadIdx.x, tx = tid & 63, ty = tid >> 6;
  __shared__ float row[CC];
  __shared__ float red[4][64];
  row[tid]     = xo[bq*CC + tid];
  row[tid+256] = xo[bq*CC + tid + 256];
  __syncthreads();
  float p = 0.f;
  for (int i = 0; i < 128; i++){
    int c = ty*128 + i;
    p = fmaf(row[c], Wo[(size_t)c*CC + co0 + tx], p);
  }
  red[ty][tx] = p;
  __syncthreads();
  if (ty == 0)
    outp[bq*CC + co0 + tx] = (red[0][tx]+red[1][tx])+(red[2][tx]+red[3][tx]);
}

// ---------------------------------------------------------------------------
extern "C" void kernel_launch(void* const* d_in, const int* in_sizes, int n_in,
                              void* d_out, int out_size, void* d_ws, size_t ws_size,
                              hipStream_t stream)
{
  const float* q   = (const float*)d_in[0];
  const float* kv  = (const float*)d_in[1];
  const float* vf  = (const float*)d_in[2];
  const float* x_r = (const float*)d_in[3];
  const float* x_w = (const float*)d_in[4];
  const float* x_k = (const float*)d_in[5];
  const float* x_v = (const float*)d_in[6];
  const float* x_a = (const float*)d_in[7];
  const float* x_g = (const float*)d_in[8];
  const float* w0  = (const float*)d_in[9];
  const float* w1  = (const float*)d_in[10];
  const float* w2  = (const float*)d_in[11];
  const float* a0  = (const float*)d_in[12];
  const float* a1  = (const float*)d_in[13];
  const float* a2  = (const float*)d_in[14];
  const float* v0  = (const float*)d_in[15];
  const float* v1  = (const float*)d_in[16];
  const float* v2  = (const float*)d_in[17];
  const float* g1  = (const float*)d_in[18];
  const float* g2  = (const float*)d_in[19];
  const float* k_k = (const float*)d_in[20];
  const float* k_a = (const float*)d_in[21];
  const float* r_k = (const float*)d_in[22];
  const float* Wr  = (const float*)d_in[23];
  const float* Wk  = (const float*)d_in[24];
  const float* Wv  = (const float*)d_in[25];
  const float* Wo  = (const float*)d_in[26];
  const float* lnw = (const float*)d_in[27];
  const float* lnb = (const float*)d_in[28];
  float* outp = (float*)d_out;
  float* ws = (float*)d_ws;

  // workspace layout (floats)
  float* xk = ws + 0;         // 4*512*512
  float* xv = ws + 1048576;
  float* kg = ws + 2097152;   // k
  float* vp = ws + 3145728;   // v_pre
  float* sv = ws + 4194304;   // sigmoid lerp factor
  float* kk = ws + 5242880;   // normalized kk
  float* Pw = ws + 6291456;   // 4*512*32
  float* Pa = ws + 6356992;
  float* Qw = ws + 6422528;   // 32*32
  float* Qa = ws + 6423552;
  float* HV = ws + 6424576;   // 4*512*32 (reuses dead th region)
  float* rr = ws + 7473152;   // 32*512
  float* gr = ws + 7489536;
  float* xo = ws + 7505920;
  float* wS = ws + 7522304;   // 32*512*512 decay
  float* kS = ws + 15910912;  // k_final
  float* bS = ws + 24299520;  // kk*a
  float* xrw = ws + 32688128; // 32*512
  float* ghw = ws + 32704512; // 32*96

  // v_first passthrough (tuple output #2)
  hipMemcpyAsync(outp + BQ*CC, vf,
                 (size_t)BQ*TT*CC*sizeof(float), hipMemcpyDeviceToDevice, stream);

  k_prep<<<32, 256, 0, stream>>>(q, kv, x_r, x_w, x_a, x_g, w1, a1, g1,
                                 Qw, Qa, ghw, xrw);
  k_rg<<<dim3(8, 32), 256, 0, stream>>>(xrw, ghw, Wr, g2, rr, gr);
  k_shift<<<1024, 256, 0, stream>>>(kv, x_k, x_v, xk, xv);
  gemm_2048_512<<<dim3(8, 32), 256, 0, stream>>>(xk, Wk, kg);
  gemm_2048_512<<<dim3(8, 32), 256, 0, stream>>>(xv, Wv, vp);
  k_pgemm<<<dim3(32, 3), 256, 0, stream>>>(kv, xv, x_w, x_a, w1, a1, v1,
                                           Pw, Pa, HV);
  k_sv<<<NB*TT, 256, 0, stream>>>(HV, v2, v0, sv);
  k_kk<<<NB*TT, 512, 0, stream>>>(kg, k_k, kk);
  k_wkb<<<BQ*TT/4, 256, 0, stream>>>(Pw, Pa, Qw, Qa, w2, a2, w0, a0, k_a,
                                     kg, kk, wS, kS, bS);
  k_scan<<<BQ*HH, 256, 0, stream>>>(wS, kS, bS, kk, vp, sv, vf, rr, gr, r_k,
                                    lnw, lnb, xo);
  k_out<<<dim3(8, 32), 256, 0, stream>>>(xo, Wo, outp);
}

// Round 8
// 656.895 us; speedup vs baseline: 3.0576x; 1.0473x over previous
//
#include <hip/hip_runtime.h>
#include <cstdint>

// Problem constants
#define TT 512   // KVLEN
#define CC 512   // C
#define HH 8     // heads
#define NN 64    // head dim
#define BQ 32    // BATCH*QLEN
#define NB 4     // BATCH

__device__ __forceinline__ float sigm(float x){ return 1.f/(1.f+__expf(-x)); }

__device__ __forceinline__ float wsum(float x){
  #pragma unroll
  for (int o=32;o;o>>=1) x += __shfl_xor(x, o, 64);
  return x;
}

// wave-uniform broadcast: register of lane `l` -> SGPR (VALU pipe, not LDS)
__device__ __forceinline__ float rlane(float x, int l){
  return __int_as_float(__builtin_amdgcn_readlane(__float_as_int(x), l));
}

// LDS-only barrier: does NOT drain vmcnt, so global prefetch loads stay in
// flight across steps.
#define LDS_BARRIER() asm volatile("s_waitcnt lgkmcnt(0)\n\ts_barrier" ::: "memory")

// ---------------------------------------------------------------------------
// k_prep: per-bq small dots (32 blocks): Qw[bq,32], Qa[bq,32], gh[bq,96],
// and xr row -> workspace.
// ---------------------------------------------------------------------------
__global__ __launch_bounds__(256) void k_prep(
  const float* __restrict__ q, const float* __restrict__ kv,
  const float* __restrict__ x_r, const float* __restrict__ x_w,
  const float* __restrict__ x_a, const float* __restrict__ x_g,
  const float* __restrict__ w1, const float* __restrict__ a1,
  const float* __restrict__ g1,
  float* __restrict__ Qw, float* __restrict__ Qa,
  float* __restrict__ ghw, float* __restrict__ xrw)
{
  int bq = blockIdx.x, b = bq >> 3, tid = threadIdx.x;
  int wave = tid >> 6, lane = tid & 63;
  __shared__ float qxw[CC], qxa[CC], sxg[CC];
  for (int c = tid; c < CC; c += 256){
    float qv = q[bq*CC + c];
    float kl = kv[((size_t)b*TT + (TT-1))*CC + c];
    xrw[bq*CC + c] = kl + (qv - kl)*x_r[c];
    sxg[c] = kl + (qv - kl)*x_g[c];
    qxw[c] = qv*x_w[c];
    qxa[c] = qv*x_a[c];
  }
  __syncthreads();
  for (int dot = wave; dot < 160; dot += 4){
    const float* buf; const float* W; int ld, dd;
    if (dot < 32)      { buf = qxw; W = w1; ld = 32; dd = dot; }
    else if (dot < 64) { buf = qxa; W = a1; ld = 32; dd = dot-32; }
    else               { buf = sxg; W = g1; ld = 96; dd = dot-64; }
    float s = 0.f;
    #pragma unroll
    for (int m = 0; m < 8; m++){
      int c = m*64 + lane;
      s = fmaf(buf[c], W[c*ld + dd], s);
    }
    s = wsum(s);
    if (lane == 0){
      if (dot < 32)      Qw[bq*32 + dd] = s;
      else if (dot < 64) Qa[bq*32 + dd] = s;
      else               ghw[bq*96 + dd] = sigm(s);
    }
  }
}

// ---------------------------------------------------------------------------
// k_rg: rrow[bq,co] = xr[bq,:]@Wr[:,co], grow[bq,co] = gh[bq,:]@g2[:,co]
// ---------------------------------------------------------------------------
__global__ __launch_bounds__(256) void k_rg(
  const float* __restrict__ xrw, const float* __restrict__ ghw,
  const float* __restrict__ Wr, const float* __restrict__ g2,
  float* __restrict__ rrow, float* __restrict__ grow)
{
  int bq = blockIdx.y; int co0 = blockIdx.x*64;
  int tid = threadIdx.x, tx = tid & 63, ty = tid >> 6;
  __shared__ float sxr[CC];
  __shared__ float sgh[96];
  __shared__ float red[4][64];
  sxr[tid]     = xrw[bq*CC + tid];
  sxr[tid+256] = xrw[bq*CC + tid + 256];
  if (tid < 96) sgh[tid] = ghw[bq*96 + tid];
  __syncthreads();
  float p = 0.f;
  for (int i = 0; i < 128; i++){
    int c = ty*128 + i;
    p = fmaf(sxr[c], Wr[(size_t)c*CC + co0 + tx], p);
  }
  red[ty][tx] = p;
  float pg = 0.f;
  for (int d = ty*24; d < ty*24 + 24; d++)
    pg = fmaf(sgh[d], g2[(size_t)d*CC + co0 + tx], pg);
  __syncthreads();
  if (ty == 0)
    rrow[bq*CC + co0 + tx] = (red[0][tx]+red[1][tx])+(red[2][tx]+red[3][tx]);
  __syncthreads();
  red[ty][tx] = pg;
  __syncthreads();
  if (ty == 0)
    grow[bq*CC + co0 + tx] = (red[0][tx]+red[1][tx])+(red[2][tx]+red[3][tx]);
}

// ---------------------------------------------------------------------------
// k_shift: elementwise token-shift mix: xk, xv.  float4, coalesced.
// ---------------------------------------------------------------------------
__global__ __launch_bounds__(256) void k_shift(
  const float* __restrict__ kv, const float* __restrict__ x_k,
  const float* __restrict__ x_v,
  float* __restrict__ xk, float* __restrict__ xv)
{
  int g = blockIdx.x*256 + threadIdx.x;      // float4 index, [0, 262144)
  int bt = g >> 7, t = bt & (TT-1), c4 = g & 127;
  const float4* kv4 = (const float4*)kv;
  float4 cur = kv4[g];
  float4 sh  = t ? kv4[g-128] : make_float4(0.f,0.f,0.f,0.f);
  float4 kc  = ((const float4*)x_k)[c4];
  float4 vc  = ((const float4*)x_v)[c4];
  float4 ok, ov;
  ok.x = cur.x + (sh.x-cur.x)*kc.x; ov.x = cur.x + (sh.x-cur.x)*vc.x;
  ok.y = cur.y + (sh.y-cur.y)*kc.y; ov.y = cur.y + (sh.y-cur.y)*vc.y;
  ok.z = cur.z + (sh.z-cur.z)*kc.z; ov.z = cur.z + (sh.z-cur.z)*vc.z;
  ok.w = cur.w + (sh.w-cur.w)*kc.w; ov.w = cur.w + (sh.w-cur.w)*vc.w;
  ((float4*)xk)[g] = ok;
  ((float4*)xv)[g] = ov;
}

// ---------------------------------------------------------------------------
// k_pgemm: three [2048x512]@[512x32] products (Pw, Pa, HV), tiled.
// ---------------------------------------------------------------------------
__global__ __launch_bounds__(256) void k_pgemm(
  const float* __restrict__ kv, const float* __restrict__ xv,
  const float* __restrict__ x_w, const float* __restrict__ x_a,
  const float* __restrict__ w1, const float* __restrict__ a1,
  const float* __restrict__ v1,
  float* __restrict__ Pw, float* __restrict__ Pa, float* __restrict__ HV)
{
  int mat = blockIdx.y;
  int r0 = blockIdx.x * 64;
  const float* A = (mat == 2) ? xv : kv;
  const float* B = (mat == 0) ? w1 : (mat == 1) ? a1 : v1;
  float* O       = (mat == 0) ? Pw : (mat == 1) ? Pa : HV;
  int tid = threadIdx.x;
  __shared__ float As[32][65];
  __shared__ float Bs[32][32];
  __shared__ float scl[CC];
  for (int c = tid; c < CC; c += 256)
    scl[c] = (mat == 0) ? (1.f - x_w[c]) : (mat == 1) ? (1.f - x_a[c]) : 1.f;
  __syncthreads();
  int tx = tid & 31, ty = tid >> 5;
  float acc[8];
  #pragma unroll
  for (int i = 0; i < 8; i++) acc[i] = 0.f;
  for (int k0 = 0; k0 < 512; k0 += 32){
    #pragma unroll
    for (int p = 0; p < 8; p++){
      int e = tid + p*256;
      int kk2 = e & 31, r = e >> 5;
      As[kk2][r] = A[(size_t)(r0+r)*512 + k0 + kk2] * scl[k0 + kk2];
    }
    #pragma unroll
    for (int p = 0; p < 4; p++){
      int e = tid + p*256;
      int n = e & 31, kk2 = e >> 5;
      Bs[kk2][n] = B[(size_t)(k0+kk2)*32 + n];
    }
    __syncthreads();
    #pragma unroll
    for (int kk2 = 0; kk2 < 32; kk2++){
      float bb = Bs[kk2][tx];
      #pragma unroll
      for (int i = 0; i < 8; i++)
        acc[i] = fmaf(As[kk2][ty*8 + i], bb, acc[i]);
    }
    __syncthreads();
  }
  #pragma unroll
  for (int i = 0; i < 8; i++)
    O[(size_t)(r0 + ty*8 + i)*32 + tx] = acc[i];
}

// ---------------------------------------------------------------------------
// k_sv: sv[bt,c] = sigm(v0[c] + HV[bt,:]@v2[:,c])
// ---------------------------------------------------------------------------
__global__ __launch_bounds__(256) void k_sv(
  const float* __restrict__ HV, const float* __restrict__ v2,
  const float* __restrict__ v0, float* __restrict__ svv)
{
  int bt = blockIdx.x, tid = threadIdx.x;
  __shared__ float hv[32];
  if (tid < 32) hv[tid] = HV[bt*32 + tid];
  __syncthreads();
  for (int c = tid; c < CC; c += 256){
    float s = 0.f;
    #pragma unroll
    for (int d = 0; d < 32; d++) s = fmaf(hv[d], v2[d*CC + c], s);
    svv[(size_t)bt*CC + c] = sigm(v0[c] + s);
  }
}

// ---------------------------------------------------------------------------
// Tiled fp32 GEMM: C[2048x512] = A[2048x512] @ W[512x512]. 64x64 tile.
// ---------------------------------------------------------------------------
__global__ __launch_bounds__(256) void gemm_2048_512(
  const float* __restrict__ A, const float* __restrict__ W, float* __restrict__ Co)
{
  __shared__ float As[32][68];
  __shared__ float Bs[32][64];
  int tid = threadIdx.x;
  int tx = tid & 15, ty = tid >> 4;
  int m0 = blockIdx.y*64, n0 = blockIdx.x*64;
  float acc[4][4];
  #pragma unroll
  for (int i=0;i<4;i++)
    #pragma unroll
    for (int j=0;j<4;j++) acc[i][j]=0.f;

  for (int k0 = 0; k0 < 512; k0 += 32){
    #pragma unroll
    for (int i = 0; i < 8; i++){
      int e = tid + i*256;
      int kk = e & 31, m = e >> 5;
      As[kk][m] = A[(size_t)(m0+m)*512 + k0 + kk];
    }
    #pragma unroll
    for (int i = 0; i < 8; i++){
      int e = tid + i*256;
      int n = e & 63, kk = e >> 6;
      Bs[kk][n] = W[(size_t)(k0+kk)*512 + n0 + n];
    }
    __syncthreads();
    #pragma unroll
    for (int kk = 0; kk < 32; kk++){
      float a4[4], b4[4];
      #pragma unroll
      for (int i=0;i<4;i++) a4[i] = As[kk][ty*4+i];
      #pragma unroll
      for (int j=0;j<4;j++) b4[j] = Bs[kk][tx*4+j];
      #pragma unroll
      for (int i=0;i<4;i++)
        #pragma unroll
        for (int j=0;j<4;j++) acc[i][j] += a4[i]*b4[j];
    }
    __syncthreads();
  }
  #pragma unroll
  for (int i=0;i<4;i++)
    #pragma unroll
    for (int j=0;j<4;j++)
      Co[(size_t)(m0+ty*4+i)*512 + n0 + tx*4 + j] = acc[i][j];
}

// ---------------------------------------------------------------------------
// K1b: kk = normalize_per_head(k * k_k)
// ---------------------------------------------------------------------------
__global__ __launch_bounds__(512) void k_kk(
  const float* __restrict__ kg, const float* __restrict__ k_k,
  float* __restrict__ kkg)
{
  int bt = blockIdx.x, tid = threadIdx.x;
  float v = kg[(size_t)bt*CC + tid]*k_k[tid];
  float ss = wsum(v*v);
  float nrm = fmaxf(sqrtf(ss), 1e-12f);
  kkg[(size_t)bt*CC + tid] = v/nrm;
}

// ---------------------------------------------------------------------------
// K2: per (bq,t,c): decay w, k_final, b_vec = kk*a.  4 rows per block.
// ---------------------------------------------------------------------------
__global__ __launch_bounds__(256) void k_wkb(
  const float* __restrict__ Pw, const float* __restrict__ Pa,
  const float* __restrict__ Qw, const float* __restrict__ Qa,
  const float* __restrict__ w2, const float* __restrict__ a2,
  const float* __restrict__ w0, const float* __restrict__ a0,
  const float* __restrict__ k_a, const float* __restrict__ kg,
  const float* __restrict__ kkg,
  float* __restrict__ wS, float* __restrict__ kS, float* __restrict__ bS)
{
  int bqt0 = blockIdx.x*4;           // 4 consecutive t within one bq
  int bq = bqt0 >> 9, t0 = bqt0 & (TT-1), b = bq >> 3;
  int tid = threadIdx.x;
  __shared__ float sth[4][32], sal[4][32];
  {
    int g = (tid >> 5) & 3, d = tid & 31;
    int pidx = ((b << 9) | (t0 + g))*32 + d;
    if (tid < 128) sth[g][d] = tanhf(Pw[pidx] + Qw[bq*32 + d]);
    else           sal[g][d] = Pa[pidx] + Qa[bq*32 + d];
  }
  __syncthreads();
  #pragma unroll
  for (int cc = 0; cc < 2; cc++){
    int c = tid + cc*256;
    float wreg[32], areg[32];
    #pragma unroll
    for (int d = 0; d < 32; d++){ wreg[d] = w2[d*CC + c]; areg[d] = a2[d*CC + c]; }
    float w0c = w0[c], a0c = a0[c], kac = k_a[c];
    #pragma unroll
    for (int g = 0; g < 4; g++){
      float wa = 0.f, aa = 0.f;
      #pragma unroll
      for (int d = 0; d < 32; d++){
        wa = fmaf(sth[g][d], wreg[d], wa);
        aa = fmaf(sal[g][d], areg[d], aa);
      }
      float a_sig = sigm(a0c + aa);
      float wdec  = __expf(-0.60653066f * sigm(w0c + wa));
      size_t bt = (size_t)((b << 9) | (t0 + g));
      size_t o  = (size_t)(bqt0 + g)*CC + c;
      float kvv = kg[bt*CC + c];
      float kkv = kkg[bt*CC + c];
      wS[o] = wdec;
      kS[o] = kvv*(1.f + (a_sig - 1.f)*kac);
      bS[o] = kkv*a_sig;
    }
  }
}

// ---------------------------------------------------------------------------
// K3: scan, 4 waves per (bq,h); wave w owns columns [16w,16w+16), lane = row.
// Coefficient broadcast is now REGISTER-ONLY: lane l of wave w holds
// {comp=l&3, col=16w+(l>>2)} of step-t data in `cur`; column jj's
// {w,k,b,kk_next} are pulled with v_readlane (VALU pipe) instead of the old
// stage-LDS round trip (16 uniform ds_read_b128/wave/step = the R6 wall).
// LDS keeps only psa (cross-wave sa partials) + vbuf (v broadcast).
// Register pipeline 3-deep (cur,nxt,nx2); global load of data(t+3) per step.
// ---------------------------------------------------------------------------
__global__ __launch_bounds__(256, 1) void k_scan(
  const float* __restrict__ wv, const float* __restrict__ kf,
  const float* __restrict__ bv, const float* __restrict__ kkg,
  const float* __restrict__ vpre, const float* __restrict__ svv,
  const float* __restrict__ vfirst,
  const float* __restrict__ rrow, const float* __restrict__ grow,
  const float* __restrict__ r_k, const float* __restrict__ ln_w,
  const float* __restrict__ ln_b, float* __restrict__ xo)
{
  __shared__ float psa[2][256];                  // [wave*64 + row]
  __shared__ float pout[256];
  __shared__ float vbuf[2][64];
  int blk = blockIdx.x; int bq = blk >> 3, h = blk & 7, b = bq >> 3;
  int tid = threadIdx.x; int wave = tid >> 6; int lane = tid & 63;
  size_t cb_bq = (size_t)bq*TT*CC + h*NN;
  size_t cb_b  = (size_t)b*TT*CC + h*NN;

  // staging role: comp 0=w, 1=k, 2=b, 3=kk@t+1
  int comp = lane & 3, col = wave*16 + (lane >> 2);
  const float* basep; size_t lbase; int tmaxl;
  if      (comp == 0){ basep = wv;  lbase = cb_bq + col;     tmaxl = TT-1; }
  else if (comp == 1){ basep = kf;  lbase = cb_bq + col;     tmaxl = TT-1; }
  else if (comp == 2){ basep = bv;  lbase = cb_bq + col;     tmaxl = TT-1; }
  else               { basep = kkg; lbase = cb_b + CC + col; tmaxl = TT-2; }

  float st[16];
  #pragma unroll
  for (int jj = 0; jj < 16; jj++) st[jj] = 0.f;
  psa[0][tid] = 0.f;

  // register pipeline: cur=data(0), nxt=data(1), nx2=data(2)
  float cur = basep[lbase];
  float nxt = basep[lbase + CC];
  float nx2 = basep[lbase + 2*CC];

  // v pipeline (wave 0): vbuf[t&1][i] = v_t[i]
  float vpc=0.f, svc=0.f, vfc=0.f, vpn=0.f, svn=0.f, vfn=0.f;
  if (wave == 0){
    float vp0 = vpre[cb_b + lane], sv0 = svv[cb_b + lane], vf0 = vfirst[cb_bq + lane];
    vbuf[0][lane] = vp0 + (vf0 - vp0)*sv0;
    vpc = vpre[cb_b + CC + lane]; svc = svv[cb_b + CC + lane]; vfc = vfirst[cb_bq + CC + lane];
    vpn = vpre[cb_b + 2*CC + lane]; svn = svv[cb_b + 2*CC + lane]; vfn = vfirst[cb_bq + 2*CC + lane];
  }
  LDS_BARRIER();

  float v_i = 0.f;
  for (int t = 0; t < TT; t++){
    float cons = cur;                       // step-t package (consumed below)
    // rotate pipeline; issue global load of data(t+3)
    cur = nxt; nxt = nx2;
    {
      int te = t+3; te = (te > tmaxl) ? tmaxl : te;
      nx2 = basep[lbase + (size_t)te*CC];
    }
    if (wave == 0){
      vbuf[(t+1)&1][lane] = vpc + (vfc - vpc)*svc;   // v_{t+1}
      vpc = vpn; svc = svn; vfc = vfn;
      int tv = (t+3 < TT) ? t+3 : TT-1;
      vpn = vpre[cb_b + (size_t)tv*CC + lane];
      svn = svv [cb_b + (size_t)tv*CC + lane];
      vfn = vfirst[cb_bq + (size_t)tv*CC + lane];
    }
    // sa from the 4 partials of step t (stride-1, conflict-free)
    float p0 = psa[t&1][lane],       p1 = psa[t&1][64 + lane];
    float p2 = psa[t&1][128 + lane], p3 = psa[t&1][192 + lane];
    float sa = -((p0 + p1) + (p2 + p3));
    v_i = vbuf[t&1][lane];

    float pn0=0.f, pn1=0.f, pn2=0.f, pn3=0.f;
    #pragma unroll
    for (int jj = 0; jj < 16; jj += 4){
      #pragma unroll
      for (int u = 0; u < 4; u++){
        int j = jj + u;
        float wj = rlane(cons, 4*j + 0);
        float kj = rlane(cons, 4*j + 1);
        float bj = rlane(cons, 4*j + 2);
        float aj = rlane(cons, 4*j + 3);
        st[j] = fmaf(st[j], wj, fmaf(sa, bj, v_i*kj));
        if      (u == 0) pn0 = fmaf(st[j], aj, pn0);
        else if (u == 1) pn1 = fmaf(st[j], aj, pn1);
        else if (u == 2) pn2 = fmaf(st[j], aj, pn2);
        else             pn3 = fmaf(st[j], aj, pn3);
      }
    }
    psa[(t+1)&1][tid] = (pn0+pn1)+(pn2+pn3);
    LDS_BARRIER();
  }

  // epilogue: out_i = sum_j S[i,j] r[j]
  {
    const float* rp = rrow + (size_t)bq*CC + h*NN;
    float po = 0.f;
    #pragma unroll
    for (int jj = 0; jj < 16; jj++) po = fmaf(st[jj], rp[wave*16 + jj], po);
    pout[tid] = po;
  }
  __syncthreads();
  if (wave == 0){
    float out = (pout[lane] + pout[64+lane]) + (pout[128+lane] + pout[192+lane]);
    float mean = wsum(out) * (1.f/NN);
    float dv = out - mean;
    float var = wsum(dv*dv) * (1.f/NN);
    float yn = dv * rsqrtf(var + 6.4e-4f);   // GN_EPS = 1e-5*64
    int c = h*NN + lane;
    float y2 = yn * ln_w[c] + ln_b[c];
    float kl = kf[cb_bq + (size_t)(TT-1)*CC + lane];
    float rl = rrow[(size_t)bq*CC + h*NN + lane];
    float rk = wsum(rl*kl*r_k[c]);
    float res = (y2 + rk*v_i) * grow[(size_t)bq*CC + c];
    xo[bq*CC + c] = res;
  }
}

// ---------------------------------------------------------------------------
// K4: out[bq,co] = xo[bq,:] @ Wo[:,co]
// ---------------------------------------------------------------------------
__global__ __launch_bounds__(256) void k_out(
  const float* __restrict__ xo, const float* __restrict__ Wo,
  float* __restrict__ outp)
{
  int bq = blockIdx.y; int co0 = blockIdx.x*64;
  int tid = threadIdx.x, tx = tid & 63, ty = tid >> 6;
  __shared__ float row[CC];
  __shared__ float red[4][64];
  row[tid]     = xo[bq*CC + tid];
  row[tid+256] = xo[bq*CC + tid + 256];
  __syncthreads();
  float p = 0.f;
  for (int i = 0; i < 128; i++){
    int c = ty*128 + i;
    p = fmaf(row[c], Wo[(size_t)c*CC + co0 + tx], p);
  }
  red[ty][tx] = p;
  __syncthreads();
  if (ty == 0)
    outp[bq*CC + co0 + tx] = (red[0][tx]+red[1][tx])+(red[2][tx]+red[3][tx]);
}

// ---------------------------------------------------------------------------
extern "C" void kernel_launch(void* const* d_in, const int* in_sizes, int n_in,
                              void* d_out, int out_size, void* d_ws, size_t ws_size,
                              hipStream_t stream)
{
  const float* q   = (const float*)d_in[0];
  const float* kv  = (const float*)d_in[1];
  const float* vf  = (const float*)d_in[2];
  const float* x_r = (const float*)d_in[3];
  const float* x_w = (const float*)d_in[4];
  const float* x_k = (const float*)d_in[5];
  const float* x_v = (const float*)d_in[6];
  const float* x_a = (const float*)d_in[7];
  const float* x_g = (const float*)d_in[8];
  const float* w0  = (const float*)d_in[9];
  const float* w1  = (const float*)d_in[10];
  const float* w2  = (const float*)d_in[11];
  const float* a0  = (const float*)d_in[12];
  const float* a1  = (const float*)d_in[13];
  const float* a2  = (const float*)d_in[14];
  const float* v0  = (const float*)d_in[15];
  const float* v1  = (const float*)d_in[16];
  const float* v2  = (const float*)d_in[17];
  const float* g1  = (const float*)d_in[18];
  const float* g2  = (const float*)d_in[19];
  const float* k_k = (const float*)d_in[20];
  const float* k_a = (const float*)d_in[21];
  const float* r_k = (const float*)d_in[22];
  const float* Wr  = (const float*)d_in[23];
  const float* Wk  = (const float*)d_in[24];
  const float* Wv  = (const float*)d_in[25];
  const float* Wo  = (const float*)d_in[26];
  const float* lnw = (const float*)d_in[27];
  const float* lnb = (const float*)d_in[28];
  float* outp = (float*)d_out;
  float* ws = (float*)d_ws;

  // workspace layout (floats)
  float* xk = ws + 0;         // 4*512*512
  float* xv = ws + 1048576;
  float* kg = ws + 2097152;   // k
  float* vp = ws + 3145728;   // v_pre
  float* sv = ws + 4194304;   // sigmoid lerp factor
  float* kk = ws + 5242880;   // normalized kk
  float* Pw = ws + 6291456;   // 4*512*32
  float* Pa = ws + 6356992;
  float* Qw = ws + 6422528;   // 32*32
  float* Qa = ws + 6423552;
  float* HV = ws + 6424576;   // 4*512*32
  float* rr = ws + 7473152;   // 32*512
  float* gr = ws + 7489536;
  float* xo = ws + 7505920;
  float* wS = ws + 7522304;   // 32*512*512 decay
  float* kS = ws + 15910912;  // k_final
  float* bS = ws + 24299520;  // kk*a
  float* xrw = ws + 32688128; // 32*512
  float* ghw = ws + 32704512; // 32*96

  // v_first passthrough (tuple output #2)
  hipMemcpyAsync(outp + BQ*CC, vf,
                 (size_t)BQ*TT*CC*sizeof(float), hipMemcpyDeviceToDevice, stream);

  k_prep<<<32, 256, 0, stream>>>(q, kv, x_r, x_w, x_a, x_g, w1, a1, g1,
                                 Qw, Qa, ghw, xrw);
  k_rg<<<dim3(8, 32), 256, 0, stream>>>(xrw, ghw, Wr, g2, rr, gr);
  k_shift<<<1024, 256, 0, stream>>>(kv, x_k, x_v, xk, xv);
  gemm_2048_512<<<dim3(8, 32), 256, 0, stream>>>(xk, Wk, kg);
  gemm_2048_512<<<dim3(8, 32), 256, 0, stream>>>(xv, Wv, vp);
  k_pgemm<<<dim3(32, 3), 256, 0, stream>>>(kv, xv, x_w, x_a, w1, a1, v1,
                                           Pw, Pa, HV);
  k_sv<<<NB*TT, 256, 0, stream>>>(HV, v2, v0, sv);
  k_kk<<<NB*TT, 512, 0, stream>>>(kg, k_k, kk);
  k_wkb<<<BQ*TT/4, 256, 0, stream>>>(Pw, Pa, Qw, Qa, w2, a2, w0, a0, k_a,
                                     kg, kk, wS, kS, bS);
  k_scan<<<BQ*HH, 256, 0, stream>>>(wS, kS, bS, kk, vp, sv, vf, rr, gr, r_k,
                                    lnw, lnb, xo);
  k_out<<<dim3(8, 32), 256, 0, stream>>>(xo, Wo, outp);
}